// Round 1
// baseline (848.437 us; speedup 1.0000x reference)
//
#include <hip/hip_runtime.h>
#include <hip/hip_bf16.h>

#define NN 50000
#define NE 800000
#define DIN 300
#define DH 96
#define DOUTC 2
#define NG 64

// ---------------- CSR build ----------------
__global__ void k_init(int* cnt, int* fill) {
    int i = blockIdx.x * blockDim.x + threadIdx.x;
    if (i < NN) { cnt[i] = 0; fill[i] = 0; }
}

__global__ void k_hist(const int* __restrict__ dst, int* cnt) {
    int e = blockIdx.x * blockDim.x + threadIdx.x;
    if (e < NE) atomicAdd(&cnt[dst[e]], 1);
}

__global__ void k_dis(const int* __restrict__ cnt, float* dis) {
    int i = blockIdx.x * blockDim.x + threadIdx.x;
    if (i < NN) dis[i] = rsqrtf(1.0f + (float)cnt[i]);
}

__global__ void k_scan(const int* __restrict__ cnt, int* rowptr) {
    __shared__ int part[1024];
    const int t = threadIdx.x;
    const int C = (NN + 1023) / 1024;
    int s0 = t * C, s1 = min(s0 + C, NN);
    if (s0 > NN) s0 = NN;
    if (s1 < s0) s1 = s0;
    int sum = 0;
    for (int i = s0; i < s1; ++i) sum += cnt[i];
    part[t] = sum;
    __syncthreads();
    for (int off = 1; off < 1024; off <<= 1) {
        int v = (t >= off) ? part[t - off] : 0;
        __syncthreads();
        part[t] += v;
        __syncthreads();
    }
    int run = (t == 0) ? 0 : part[t - 1];
    for (int i = s0; i < s1; ++i) { rowptr[i] = run; run += cnt[i]; }
    if (t == 1023) rowptr[NN] = run;
}

__global__ void k_scatter(const int* __restrict__ src, const int* __restrict__ dst,
                          const int* __restrict__ rowptr, int* fill, int* esrc) {
    int e = blockIdx.x * blockDim.x + threadIdx.x;
    if (e < NE) {
        int d = dst[e];
        int pos = rowptr[d] + atomicAdd(&fill[d], 1);
        esrc[pos] = src[e];
    }
}

// ---------------- GEMM: C[M][96] = A[M][K] @ W[K][96] ----------------
template <int K, int KT>
__global__ void k_gemm(const float* __restrict__ A, const float* __restrict__ W,
                       float* __restrict__ C, int M) {
    constexpr int MT = 128;
    __shared__ float As[MT][KT];
    __shared__ float Ws[KT][96];
    const int tid = threadIdx.x;          // 256 threads
    const int tx = tid & 15;              // col group: 6 cols
    const int ty = tid >> 4;              // row group: 8 rows
    const int row0 = blockIdx.x * MT;
    float acc[8][6];
    #pragma unroll
    for (int r = 0; r < 8; ++r)
        #pragma unroll
        for (int j = 0; j < 6; ++j) acc[r][j] = 0.f;

    for (int k0 = 0; k0 < K; k0 += KT) {
        for (int i = tid; i < MT * KT; i += 256) {
            int r = i / KT, k = i - r * KT;
            int row = row0 + r;
            As[r][k] = (row < M) ? A[row * K + k0 + k] : 0.f;
        }
        for (int i = tid; i < KT * 96; i += 256) {
            int k = i / 96, j = i - k * 96;
            Ws[k][j] = W[(k0 + k) * 96 + j];
        }
        __syncthreads();
        for (int k = 0; k < KT; ++k) {
            float av[8], wv[6];
            #pragma unroll
            for (int r = 0; r < 8; ++r) av[r] = As[ty * 8 + r][k];
            #pragma unroll
            for (int j = 0; j < 6; ++j) wv[j] = Ws[k][tx * 6 + j];
            #pragma unroll
            for (int r = 0; r < 8; ++r)
                #pragma unroll
                for (int j = 0; j < 6; ++j) acc[r][j] += av[r] * wv[j];
        }
        __syncthreads();
    }
    #pragma unroll
    for (int r = 0; r < 8; ++r) {
        int row = row0 + ty * 8 + r;
        if (row < M) {
            #pragma unroll
            for (int j = 0; j < 6; ++j) C[row * 96 + tx * 6 + j] = acc[r][j];
        }
    }
}

// ---------------- aggregate + bias + relu ----------------
// hout[n][f] = relu( dis[n]*( sum_e dis[esrc_e]*ht[esrc_e][f] + dis[n]*ht[n][f] ) + b[f] )
__global__ void k_agg(const float* __restrict__ ht, const float* __restrict__ dis,
                      const int* __restrict__ rowptr, const int* __restrict__ esrc,
                      const float* __restrict__ bias, float* __restrict__ hout) {
    int gid = blockIdx.x * blockDim.x + threadIdx.x;
    if (gid >= NN * DH) return;
    int n = gid / DH;
    int f = gid - n * DH;
    int beg = rowptr[n], end = rowptr[n + 1];
    float dn = dis[n];
    float acc = dn * ht[n * DH + f];
    for (int e = beg; e < end; ++e) {
        int s = esrc[e];
        acc += dis[s] * ht[s * DH + f];
    }
    float v = dn * acc + bias[f];
    hout[gid] = fmaxf(v, 0.f);
}

// ---------------- mean-pool per graph + FC ----------------
__global__ void k_pool_fc(const float* __restrict__ h, const int* __restrict__ batch,
                          const float* __restrict__ Wfc, const float* __restrict__ bfc,
                          float* __restrict__ out) {
    __shared__ float pooled[DH];
    const int g = blockIdx.x;
    // lower_bound(batch, g)
    int lo = 0, hi = NN;
    while (lo < hi) { int mid = (lo + hi) >> 1; if (batch[mid] < g) lo = mid + 1; else hi = mid; }
    const int s = lo;
    hi = NN;
    while (lo < hi) { int mid = (lo + hi) >> 1; if (batch[mid] < g + 1) lo = mid + 1; else hi = mid; }
    const int e = lo;
    const int f = threadIdx.x;   // 128 threads
    if (f < DH) {
        float sum = 0.f;
        for (int n = s; n < e; ++n) sum += h[n * DH + f];
        float cntf = (float)(e - s);
        pooled[f] = sum / fmaxf(cntf, 1.f);
    }
    __syncthreads();
    if (f < DOUTC) {
        float acc = bfc[f];
        #pragma unroll 8
        for (int j = 0; j < DH; ++j) acc += pooled[j] * Wfc[j * DOUTC + f];
        out[g * DOUTC + f] = acc;
    }
}

extern "C" void kernel_launch(void* const* d_in, const int* in_sizes, int n_in,
                              void* d_out, int out_size, void* d_ws, size_t ws_size,
                              hipStream_t stream) {
    const float* x   = (const float*)d_in[0];
    const float* W1  = (const float*)d_in[1];
    const float* b1  = (const float*)d_in[2];
    const float* W2  = (const float*)d_in[3];
    const float* b2  = (const float*)d_in[4];
    const float* Wfc = (const float*)d_in[5];
    const float* bfc = (const float*)d_in[6];
    const int* src   = (const int*)d_in[7];
    const int* dst   = (const int*)d_in[8];
    const int* batch = (const int*)d_in[9];
    float* out = (float*)d_out;

    // workspace layout (all fp32/int32, ~42.5 MB)
    float* ht   = (float*)d_ws;            // NN*DH
    float* hbuf = ht + (size_t)NN * DH;    // NN*DH
    float* dis  = hbuf + (size_t)NN * DH;  // NN
    int* cnt    = (int*)(dis + NN);        // NN
    int* fill   = cnt + NN;                // NN
    int* rowptr = fill + NN;               // NN+1
    int* esrc   = rowptr + NN + 2;         // NE

    const int TB = 256;
    // CSR build + degrees
    k_init<<<(NN + TB - 1) / TB, TB, 0, stream>>>(cnt, fill);
    k_hist<<<(NE + TB - 1) / TB, TB, 0, stream>>>(dst, cnt);
    k_dis<<<(NN + TB - 1) / TB, TB, 0, stream>>>(cnt, dis);
    k_scan<<<1, 1024, 0, stream>>>(cnt, rowptr);
    k_scatter<<<(NE + TB - 1) / TB, TB, 0, stream>>>(src, dst, rowptr, fill, esrc);

    // layer 1
    k_gemm<DIN, 50><<<(NN + 127) / 128, 256, 0, stream>>>(x, W1, ht, NN);
    k_agg<<<(NN * DH + TB - 1) / TB, TB, 0, stream>>>(ht, dis, rowptr, esrc, b1, hbuf);
    // layer 2
    k_gemm<DH, 48><<<(NN + 127) / 128, 256, 0, stream>>>(hbuf, W2, ht, NN);
    k_agg<<<(NN * DH + TB - 1) / TB, TB, 0, stream>>>(ht, dis, rowptr, esrc, b2, hbuf);
    // pool + fc
    k_pool_fc<<<NG, 128, 0, stream>>>(hbuf, batch, Wfc, bfc, out);
}

// Round 2
// 566.072 us; speedup vs baseline: 1.4988x; 1.4988x over previous
//
#include <hip/hip_runtime.h>
#include <hip/hip_bf16.h>

#define NN 50000
#define NE 800000
#define DIN 300
#define DH 96
#define DOUTC 2
#define NG 64

// ---------------- CSR build ----------------
__global__ void k_init(int* cnt, int* fill, float* pooled, int* gcnt) {
    int i = blockIdx.x * blockDim.x + threadIdx.x;
    if (i < NN) { cnt[i] = 0; fill[i] = 0; }
    if (i < NG * DH) pooled[i] = 0.f;
    if (i < NG) gcnt[i] = 0;
}

__global__ void k_hist(const int* __restrict__ dst, int* cnt) {
    int e = blockIdx.x * blockDim.x + threadIdx.x;
    if (e < NE) atomicAdd(&cnt[dst[e]], 1);
}

__global__ void k_dis(const int* __restrict__ cnt, float* dis) {
    int i = blockIdx.x * blockDim.x + threadIdx.x;
    if (i < NN) dis[i] = rsqrtf(1.0f + (float)cnt[i]);
}

__global__ void k_scan(const int* __restrict__ cnt, int* rowptr) {
    __shared__ int part[1024];
    const int t = threadIdx.x;
    const int C = (NN + 1023) / 1024;
    int s0 = t * C, s1 = min(s0 + C, NN);
    if (s0 > NN) s0 = NN;
    if (s1 < s0) s1 = s0;
    int sum = 0;
    for (int i = s0; i < s1; ++i) sum += cnt[i];
    part[t] = sum;
    __syncthreads();
    for (int off = 1; off < 1024; off <<= 1) {
        int v = (t >= off) ? part[t - off] : 0;
        __syncthreads();
        part[t] += v;
        __syncthreads();
    }
    int run = (t == 0) ? 0 : part[t - 1];
    for (int i = s0; i < s1; ++i) { rowptr[i] = run; run += cnt[i]; }
    if (t == 1023) rowptr[NN] = run;
}

__global__ void k_scatter(const int* __restrict__ src, const int* __restrict__ dst,
                          const int* __restrict__ rowptr, int* fill, int* esrc) {
    int e = blockIdx.x * blockDim.x + threadIdx.x;
    if (e < NE) {
        int d = dst[e];
        int pos = rowptr[d] + atomicAdd(&fill[d], 1);
        esrc[pos] = src[e];
    }
}

// ---------------- GEMM: C[M][96] = A[M][K] @ W[K][96] ----------------
template <int K, int KT>
__global__ void k_gemm(const float* __restrict__ A, const float* __restrict__ W,
                       float* __restrict__ C, int M) {
    constexpr int MT = 128;
    __shared__ float As[MT][KT];
    __shared__ float Ws[KT][96];
    const int tid = threadIdx.x;          // 256 threads
    const int tx = tid & 15;              // col group: 6 cols
    const int ty = tid >> 4;              // row group: 8 rows
    const int row0 = blockIdx.x * MT;
    float acc[8][6];
    #pragma unroll
    for (int r = 0; r < 8; ++r)
        #pragma unroll
        for (int j = 0; j < 6; ++j) acc[r][j] = 0.f;

    for (int k0 = 0; k0 < K; k0 += KT) {
        for (int i = tid; i < MT * KT; i += 256) {
            int r = i / KT, k = i - r * KT;
            int row = row0 + r;
            As[r][k] = (row < M) ? A[row * K + k0 + k] : 0.f;
        }
        for (int i = tid; i < KT * 96; i += 256) {
            int k = i / 96, j = i - k * 96;
            Ws[k][j] = W[(k0 + k) * 96 + j];
        }
        __syncthreads();
        for (int k = 0; k < KT; ++k) {
            float av[8], wv[6];
            #pragma unroll
            for (int r = 0; r < 8; ++r) av[r] = As[ty * 8 + r][k];
            #pragma unroll
            for (int j = 0; j < 6; ++j) wv[j] = Ws[k][tx * 6 + j];
            #pragma unroll
            for (int r = 0; r < 8; ++r)
                #pragma unroll
                for (int j = 0; j < 6; ++j) acc[r][j] += av[r] * wv[j];
        }
        __syncthreads();
    }
    #pragma unroll
    for (int r = 0; r < 8; ++r) {
        int row = row0 + ty * 8 + r;
        if (row < M) {
            #pragma unroll
            for (int j = 0; j < 6; ++j) C[row * 96 + tx * 6 + j] = acc[r][j];
        }
    }
}

// ---------------- aggregate + bias + relu (float4 lanes) ----------------
// hout[n][f] = relu( dis[n]*( sum_e dis[esrc_e]*ht[esrc_e][f] + dis[n]*ht[n][f] ) + b[f] )
#define QH (DH / 4)   // 24 float4 per node
__global__ void k_agg(const float4* __restrict__ ht4, const float* __restrict__ dis,
                      const int* __restrict__ rowptr, const int* __restrict__ esrc,
                      const float4* __restrict__ bias4, float4* __restrict__ hout4) {
    int gid = blockIdx.x * blockDim.x + threadIdx.x;
    if (gid >= NN * QH) return;
    int n = gid / QH;
    int q = gid - n * QH;
    int beg = rowptr[n], end = rowptr[n + 1];
    float dn = dis[n];
    float4 h0 = ht4[(size_t)n * QH + q];
    float4 acc = make_float4(dn * h0.x, dn * h0.y, dn * h0.z, dn * h0.w);
    for (int e = beg; e < end; ++e) {
        int s = esrc[e];
        float ds = dis[s];
        float4 v = ht4[(size_t)s * QH + q];
        acc.x = fmaf(ds, v.x, acc.x);
        acc.y = fmaf(ds, v.y, acc.y);
        acc.z = fmaf(ds, v.z, acc.z);
        acc.w = fmaf(ds, v.w, acc.w);
    }
    float4 b = bias4[q];
    float4 r;
    r.x = fmaxf(fmaf(dn, acc.x, b.x), 0.f);
    r.y = fmaxf(fmaf(dn, acc.y, b.y), 0.f);
    r.z = fmaxf(fmaf(dn, acc.z, b.z), 0.f);
    r.w = fmaxf(fmaf(dn, acc.w, b.w), 0.f);
    hout4[gid] = r;
}

// ---------------- mean-pool: node-parallel partial sums ----------------
#define PNODES 128
__global__ void k_pool_partial(const float* __restrict__ h, const int* __restrict__ batch,
                               float* __restrict__ pooled, int* __restrict__ gcnt) {
    __shared__ int sbatch[PNODES];
    const int n0 = blockIdx.x * PNODES;
    const int nend = min(n0 + PNODES, NN);
    const int cnt = nend - n0;
    const int f = threadIdx.x;   // 128 threads
    if (f < cnt) sbatch[f] = batch[n0 + f];
    __syncthreads();
    if (f < DH) {
        float acc = 0.f;
        int cur = sbatch[0];
        for (int i = 0; i < cnt; ++i) {
            int g = sbatch[i];
            if (g != cur) {
                atomicAdd(&pooled[cur * DH + f], acc);
                acc = 0.f; cur = g;
            }
            acc += h[(size_t)(n0 + i) * DH + f];
        }
        atomicAdd(&pooled[cur * DH + f], acc);
    } else if (f == DH) {
        int c = 0;
        int cur = sbatch[0];
        for (int i = 0; i < cnt; ++i) {
            int g = sbatch[i];
            if (g != cur) { atomicAdd(&gcnt[cur], c); c = 0; cur = g; }
            ++c;
        }
        atomicAdd(&gcnt[cur], c);
    }
}

__global__ void k_fc(const float* __restrict__ pooled, const int* __restrict__ gcnt,
                     const float* __restrict__ Wfc, const float* __restrict__ bfc,
                     float* __restrict__ out) {
    const int t = threadIdx.x;   // 128 threads: (g, c)
    if (t >= NG * DOUTC) return;
    const int g = t / DOUTC;
    const int c = t - g * DOUTC;
    float inv = 1.f / fmaxf((float)gcnt[g], 1.f);
    float acc = bfc[c];
    #pragma unroll 8
    for (int j = 0; j < DH; ++j)
        acc += pooled[g * DH + j] * inv * Wfc[j * DOUTC + c];
    out[g * DOUTC + c] = acc;
}

extern "C" void kernel_launch(void* const* d_in, const int* in_sizes, int n_in,
                              void* d_out, int out_size, void* d_ws, size_t ws_size,
                              hipStream_t stream) {
    const float* x   = (const float*)d_in[0];
    const float* W1  = (const float*)d_in[1];
    const float* b1  = (const float*)d_in[2];
    const float* W2  = (const float*)d_in[3];
    const float* b2  = (const float*)d_in[4];
    const float* Wfc = (const float*)d_in[5];
    const float* bfc = (const float*)d_in[6];
    const int* src   = (const int*)d_in[7];
    const int* dst   = (const int*)d_in[8];
    const int* batch = (const int*)d_in[9];
    float* out = (float*)d_out;

    // workspace layout
    float* ht    = (float*)d_ws;              // NN*DH
    float* hbuf  = ht + (size_t)NN * DH;      // NN*DH
    float* dis   = hbuf + (size_t)NN * DH;    // NN
    float* pooled= dis + NN;                  // NG*DH
    int* cnt     = (int*)(pooled + NG * DH);  // NN
    int* fill    = cnt + NN;                  // NN
    int* gcnt    = fill + NN;                 // NG
    int* rowptr  = gcnt + NG;                 // NN+1
    int* esrc    = rowptr + NN + 2;           // NE

    const int TB = 256;
    // CSR build + degrees + zero-init of pooled/gcnt
    k_init<<<(NN + TB - 1) / TB, TB, 0, stream>>>(cnt, fill, pooled, gcnt);
    k_hist<<<(NE + TB - 1) / TB, TB, 0, stream>>>(dst, cnt);
    k_dis<<<(NN + TB - 1) / TB, TB, 0, stream>>>(cnt, dis);
    k_scan<<<1, 1024, 0, stream>>>(cnt, rowptr);
    k_scatter<<<(NE + TB - 1) / TB, TB, 0, stream>>>(src, dst, rowptr, fill, esrc);

    // layer 1
    k_gemm<DIN, 50><<<(NN + 127) / 128, 256, 0, stream>>>(x, W1, ht, NN);
    k_agg<<<(NN * QH + TB - 1) / TB, TB, 0, stream>>>(
        (const float4*)ht, dis, rowptr, esrc, (const float4*)b1, (float4*)hbuf);
    // layer 2
    k_gemm<DH, 48><<<(NN + 127) / 128, 256, 0, stream>>>(hbuf, W2, ht, NN);
    k_agg<<<(NN * QH + TB - 1) / TB, TB, 0, stream>>>(
        (const float4*)ht, dis, rowptr, esrc, (const float4*)b2, (float4*)hbuf);
    // pool + fc
    k_pool_partial<<<(NN + PNODES - 1) / PNODES, 128, 0, stream>>>(hbuf, batch, pooled, gcnt);
    k_fc<<<1, 128, 0, stream>>>(pooled, gcnt, Wfc, bfc, out);
}

// Round 3
// 536.154 us; speedup vs baseline: 1.5824x; 1.0558x over previous
//
#include <hip/hip_runtime.h>
#include <hip/hip_bf16.h>

#define NN 50000
#define NE 800000
#define DIN 300
#define DH 96
#define DOUTC 2
#define NG 64

// ---------------- CSR build ----------------
__global__ void k_init(int* cnt, int* fill, float* pooled, int* gcnt) {
    int i = blockIdx.x * blockDim.x + threadIdx.x;
    if (i < NN) { cnt[i] = 0; fill[i] = 0; }
    if (i < NG * DH) pooled[i] = 0.f;
    if (i < NG) gcnt[i] = 0;
}

__global__ void k_hist(const int* __restrict__ dst, int* cnt) {
    int e = blockIdx.x * blockDim.x + threadIdx.x;
    if (e < NE) atomicAdd(&cnt[dst[e]], 1);
}

__global__ void k_dis(const int* __restrict__ cnt, float* dis) {
    int i = blockIdx.x * blockDim.x + threadIdx.x;
    if (i < NN) dis[i] = rsqrtf(1.0f + (float)cnt[i]);
}

__global__ void k_scan(const int* __restrict__ cnt, int* rowptr) {
    __shared__ int part[1024];
    const int t = threadIdx.x;
    const int C = (NN + 1023) / 1024;
    int s0 = t * C, s1 = min(s0 + C, NN);
    if (s0 > NN) s0 = NN;
    if (s1 < s0) s1 = s0;
    int sum = 0;
    for (int i = s0; i < s1; ++i) sum += cnt[i];
    part[t] = sum;
    __syncthreads();
    for (int off = 1; off < 1024; off <<= 1) {
        int v = (t >= off) ? part[t - off] : 0;
        __syncthreads();
        part[t] += v;
        __syncthreads();
    }
    int run = (t == 0) ? 0 : part[t - 1];
    for (int i = s0; i < s1; ++i) { rowptr[i] = run; run += cnt[i]; }
    if (t == 1023) rowptr[NN] = run;
}

__global__ void k_scatter(const int* __restrict__ src, const int* __restrict__ dst,
                          const int* __restrict__ rowptr, int* fill, int* esrc) {
    int e = blockIdx.x * blockDim.x + threadIdx.x;
    if (e < NE) {
        int d = dst[e];
        int pos = rowptr[d] + atomicAdd(&fill[d], 1);
        esrc[pos] = src[e];
    }
}

// ---------------- GEMM: C[M][96] = A[M][K] @ W[K][96] ----------------
// MT=64 rows/block, 256 threads, 4x6 acc/thread. Grid ~782 blocks -> ~3 blocks/CU.
template <int K, int KT>
__global__ void k_gemm(const float* __restrict__ A, const float* __restrict__ W,
                       float* __restrict__ C, int M) {
    constexpr int MT = 64;
    __shared__ float As[MT][KT];
    __shared__ float Ws[KT][96];
    const int tid = threadIdx.x;          // 256 threads
    const int tx = tid & 15;              // col group: 6 cols
    const int ty = tid >> 4;              // row group: 4 rows
    const int row0 = blockIdx.x * MT;
    float acc[4][6];
    #pragma unroll
    for (int r = 0; r < 4; ++r)
        #pragma unroll
        for (int j = 0; j < 6; ++j) acc[r][j] = 0.f;

    for (int k0 = 0; k0 < K; k0 += KT) {
        for (int i = tid; i < MT * KT; i += 256) {
            int r = i / KT, k = i - r * KT;
            int row = row0 + r;
            As[r][k] = (row < M) ? A[row * K + k0 + k] : 0.f;
        }
        for (int i = tid; i < KT * 96; i += 256) {
            int k = i / 96, j = i - k * 96;
            Ws[k][j] = W[(k0 + k) * 96 + j];
        }
        __syncthreads();
        #pragma unroll 2
        for (int k = 0; k < KT; ++k) {
            float av[4], wv[6];
            #pragma unroll
            for (int r = 0; r < 4; ++r) av[r] = As[ty * 4 + r][k];
            #pragma unroll
            for (int j = 0; j < 6; ++j) wv[j] = Ws[k][tx * 6 + j];
            #pragma unroll
            for (int r = 0; r < 4; ++r)
                #pragma unroll
                for (int j = 0; j < 6; ++j) acc[r][j] = fmaf(av[r], wv[j], acc[r][j]);
        }
        __syncthreads();
    }
    #pragma unroll
    for (int r = 0; r < 4; ++r) {
        int row = row0 + ty * 4 + r;
        if (row < M) {
            #pragma unroll
            for (int j = 0; j < 6; ++j) C[row * 96 + tx * 6 + j] = acc[r][j];
        }
    }
}

// ---------------- aggregate + bias + relu (float4 lanes) ----------------
// hout[n][f] = relu( dis[n]*( sum_e dis[esrc_e]*ht[esrc_e][f] + dis[n]*ht[n][f] ) + b[f] )
#define QH (DH / 4)   // 24 float4 per node
__global__ void k_agg(const float4* __restrict__ ht4, const float* __restrict__ dis,
                      const int* __restrict__ rowptr, const int* __restrict__ esrc,
                      const float4* __restrict__ bias4, float4* __restrict__ hout4) {
    int gid = blockIdx.x * blockDim.x + threadIdx.x;
    if (gid >= NN * QH) return;
    int n = gid / QH;
    int q = gid - n * QH;
    int beg = rowptr[n], end = rowptr[n + 1];
    float dn = dis[n];
    float4 h0 = ht4[(size_t)n * QH + q];
    float4 acc = make_float4(dn * h0.x, dn * h0.y, dn * h0.z, dn * h0.w);
    for (int e = beg; e < end; ++e) {
        int s = esrc[e];
        float ds = dis[s];
        float4 v = ht4[(size_t)s * QH + q];
        acc.x = fmaf(ds, v.x, acc.x);
        acc.y = fmaf(ds, v.y, acc.y);
        acc.z = fmaf(ds, v.z, acc.z);
        acc.w = fmaf(ds, v.w, acc.w);
    }
    float4 b = bias4[q];
    float4 r;
    r.x = fmaxf(fmaf(dn, acc.x, b.x), 0.f);
    r.y = fmaxf(fmaf(dn, acc.y, b.y), 0.f);
    r.z = fmaxf(fmaf(dn, acc.z, b.z), 0.f);
    r.w = fmaxf(fmaf(dn, acc.w, b.w), 0.f);
    hout4[gid] = r;
}

// ---------------- mean-pool: node-parallel partial sums ----------------
#define PNODES 128
__global__ void k_pool_partial(const float* __restrict__ h, const int* __restrict__ batch,
                               float* __restrict__ pooled, int* __restrict__ gcnt) {
    __shared__ int sbatch[PNODES];
    const int n0 = blockIdx.x * PNODES;
    const int nend = min(n0 + PNODES, NN);
    const int cnt = nend - n0;
    const int f = threadIdx.x;   // 128 threads
    if (f < cnt) sbatch[f] = batch[n0 + f];
    __syncthreads();
    if (f < DH) {
        float acc = 0.f;
        int cur = sbatch[0];
        for (int i = 0; i < cnt; ++i) {
            int g = sbatch[i];
            if (g != cur) {
                atomicAdd(&pooled[cur * DH + f], acc);
                acc = 0.f; cur = g;
            }
            acc += h[(size_t)(n0 + i) * DH + f];
        }
        atomicAdd(&pooled[cur * DH + f], acc);
    } else if (f == DH) {
        int c = 0;
        int cur = sbatch[0];
        for (int i = 0; i < cnt; ++i) {
            int g = sbatch[i];
            if (g != cur) { atomicAdd(&gcnt[cur], c); c = 0; cur = g; }
            ++c;
        }
        atomicAdd(&gcnt[cur], c);
    }
}

__global__ void k_fc(const float* __restrict__ pooled, const int* __restrict__ gcnt,
                     const float* __restrict__ Wfc, const float* __restrict__ bfc,
                     float* __restrict__ out) {
    const int t = threadIdx.x;   // 128 threads: (g, c)
    if (t >= NG * DOUTC) return;
    const int g = t / DOUTC;
    const int c = t - g * DOUTC;
    float inv = 1.f / fmaxf((float)gcnt[g], 1.f);
    float acc = bfc[c];
    #pragma unroll 8
    for (int j = 0; j < DH; ++j)
        acc += pooled[g * DH + j] * inv * Wfc[j * DOUTC + c];
    out[g * DOUTC + c] = acc;
}

extern "C" void kernel_launch(void* const* d_in, const int* in_sizes, int n_in,
                              void* d_out, int out_size, void* d_ws, size_t ws_size,
                              hipStream_t stream) {
    const float* x   = (const float*)d_in[0];
    const float* W1  = (const float*)d_in[1];
    const float* b1  = (const float*)d_in[2];
    const float* W2  = (const float*)d_in[3];
    const float* b2  = (const float*)d_in[4];
    const float* Wfc = (const float*)d_in[5];
    const float* bfc = (const float*)d_in[6];
    const int* src   = (const int*)d_in[7];
    const int* dst   = (const int*)d_in[8];
    const int* batch = (const int*)d_in[9];
    float* out = (float*)d_out;

    // workspace layout
    float* ht    = (float*)d_ws;              // NN*DH
    float* hbuf  = ht + (size_t)NN * DH;      // NN*DH
    float* dis   = hbuf + (size_t)NN * DH;    // NN
    float* pooled= dis + NN;                  // NG*DH
    int* cnt     = (int*)(pooled + NG * DH);  // NN
    int* fill    = cnt + NN;                  // NN
    int* gcnt    = fill + NN;                 // NG
    int* rowptr  = gcnt + NG;                 // NN+1
    int* esrc    = rowptr + NN + 2;           // NE

    const int TB = 256;
    // CSR build + degrees + zero-init of pooled/gcnt
    k_init<<<(NN + TB - 1) / TB, TB, 0, stream>>>(cnt, fill, pooled, gcnt);
    k_hist<<<(NE + TB - 1) / TB, TB, 0, stream>>>(dst, cnt);
    k_dis<<<(NN + TB - 1) / TB, TB, 0, stream>>>(cnt, dis);
    k_scan<<<1, 1024, 0, stream>>>(cnt, rowptr);
    k_scatter<<<(NE + TB - 1) / TB, TB, 0, stream>>>(src, dst, rowptr, fill, esrc);

    // layer 1
    k_gemm<DIN, 50><<<(NN + 63) / 64, 256, 0, stream>>>(x, W1, ht, NN);
    k_agg<<<(NN * QH + TB - 1) / TB, TB, 0, stream>>>(
        (const float4*)ht, dis, rowptr, esrc, (const float4*)b1, (float4*)hbuf);
    // layer 2
    k_gemm<DH, 48><<<(NN + 63) / 64, 256, 0, stream>>>(hbuf, W2, ht, NN);
    k_agg<<<(NN * QH + TB - 1) / TB, TB, 0, stream>>>(
        (const float4*)ht, dis, rowptr, esrc, (const float4*)b2, (float4*)hbuf);
    // pool + fc
    k_pool_partial<<<(NN + PNODES - 1) / PNODES, 128, 0, stream>>>(hbuf, batch, pooled, gcnt);
    k_fc<<<1, 128, 0, stream>>>(pooled, gcnt, Wfc, bfc, out);
}

// Round 4
// 517.112 us; speedup vs baseline: 1.6407x; 1.0368x over previous
//
#include <hip/hip_runtime.h>
#include <hip/hip_bf16.h>

#define NN 50000
#define NE 800000
#define DIN 300
#define DH 96
#define DOUTC 2
#define NG 64

// ---------------- CSR build ----------------
__global__ void k_init(int* cnt, int* fill, float* pooled, int* gcnt) {
    int i = blockIdx.x * blockDim.x + threadIdx.x;
    if (i < NN) { cnt[i] = 0; fill[i] = 0; }
    if (i < NG * DH) pooled[i] = 0.f;
    if (i < NG) gcnt[i] = 0;
}

__global__ void k_hist(const int* __restrict__ dst, int* cnt) {
    int e = blockIdx.x * blockDim.x + threadIdx.x;
    if (e < NE) atomicAdd(&cnt[dst[e]], 1);
}

__global__ void k_dis(const int* __restrict__ cnt, float* dis) {
    int i = blockIdx.x * blockDim.x + threadIdx.x;
    if (i < NN) dis[i] = rsqrtf(1.0f + (float)cnt[i]);
}

__global__ void k_scan(const int* __restrict__ cnt, int* rowptr) {
    __shared__ int part[1024];
    const int t = threadIdx.x;
    const int C = (NN + 1023) / 1024;
    int s0 = t * C, s1 = min(s0 + C, NN);
    if (s0 > NN) s0 = NN;
    if (s1 < s0) s1 = s0;
    int sum = 0;
    for (int i = s0; i < s1; ++i) sum += cnt[i];
    part[t] = sum;
    __syncthreads();
    for (int off = 1; off < 1024; off <<= 1) {
        int v = (t >= off) ? part[t - off] : 0;
        __syncthreads();
        part[t] += v;
        __syncthreads();
    }
    int run = (t == 0) ? 0 : part[t - 1];
    for (int i = s0; i < s1; ++i) { rowptr[i] = run; run += cnt[i]; }
    if (t == 1023) rowptr[NN] = run;
}

__global__ void k_scatter(const int* __restrict__ src, const int* __restrict__ dst,
                          const int* __restrict__ rowptr, int* fill, int* esrc) {
    int e = blockIdx.x * blockDim.x + threadIdx.x;
    if (e < NE) {
        int d = dst[e];
        int pos = rowptr[d] + atomicAdd(&fill[d], 1);
        esrc[pos] = src[e];
    }
}

// ---------------- GEMM: C[M][96] = A[M][K] @ W[K][96] ----------------
// 128 threads, tile 64x96, per-thread 4 rows x 12 cols, all-b128 LDS traffic.
// Per k-step/wave: 48 FMA (96 cyc) vs 4 ds_read_b128 (48 cyc) -> VALU-bound.
template <int K, int KT>
__global__ void k_gemm(const float* __restrict__ A, const float* __restrict__ W,
                       float* __restrict__ C, int M) {
    constexpr int MT = 64;
    constexpr int KQ = KT / 4;
    __shared__ float As[MT * KT];
    __shared__ float Ws[KT * 96];
    const int tid = threadIdx.x;          // 128 threads
    const int tx = tid & 7;               // 8 col groups x 12 cols
    const int ty = tid >> 3;              // 16 row slots; rows = ty + 16*r
    const int row0 = blockIdx.x * MT;
    float acc[4][12];
    #pragma unroll
    for (int r = 0; r < 4; ++r)
        #pragma unroll
        for (int j = 0; j < 12; ++j) acc[r][j] = 0.f;

    for (int k0 = 0; k0 < K; k0 += KT) {
        // stage A: float4, coalesced; rows guarded (zero-fill OOB)
        for (int i = tid; i < MT * KQ; i += 128) {
            int r = i / KQ, kq = i - r * KQ;
            int row = row0 + r;
            float4 v = make_float4(0.f, 0.f, 0.f, 0.f);
            if (row < M) v = *(const float4*)&A[(size_t)row * K + k0 + kq * 4];
            *(float4*)&As[r * KT + kq * 4] = v;
        }
        // stage W: float4, coalesced
        for (int i = tid; i < KT * 24; i += 128) {
            int k = i / 24, cq = i - k * 24;
            *(float4*)&Ws[k * 96 + cq * 4] = *(const float4*)&W[(size_t)(k0 + k) * 96 + cq * 4];
        }
        __syncthreads();
        #pragma unroll
        for (int kk = 0; kk < KT; kk += 4) {
            float4 av[4];
            #pragma unroll
            for (int r = 0; r < 4; ++r)
                av[r] = *(const float4*)&As[(ty + 16 * r) * KT + kk];
            #pragma unroll
            for (int k2 = 0; k2 < 4; ++k2) {
                float4 w0 = *(const float4*)&Ws[(kk + k2) * 96 + tx * 12];
                float4 w1 = *(const float4*)&Ws[(kk + k2) * 96 + tx * 12 + 4];
                float4 w2 = *(const float4*)&Ws[(kk + k2) * 96 + tx * 12 + 8];
                #pragma unroll
                for (int r = 0; r < 4; ++r) {
                    float a = (k2 == 0) ? av[r].x : (k2 == 1) ? av[r].y : (k2 == 2) ? av[r].z : av[r].w;
                    acc[r][0]  = fmaf(a, w0.x, acc[r][0]);
                    acc[r][1]  = fmaf(a, w0.y, acc[r][1]);
                    acc[r][2]  = fmaf(a, w0.z, acc[r][2]);
                    acc[r][3]  = fmaf(a, w0.w, acc[r][3]);
                    acc[r][4]  = fmaf(a, w1.x, acc[r][4]);
                    acc[r][5]  = fmaf(a, w1.y, acc[r][5]);
                    acc[r][6]  = fmaf(a, w1.z, acc[r][6]);
                    acc[r][7]  = fmaf(a, w1.w, acc[r][7]);
                    acc[r][8]  = fmaf(a, w2.x, acc[r][8]);
                    acc[r][9]  = fmaf(a, w2.y, acc[r][9]);
                    acc[r][10] = fmaf(a, w2.z, acc[r][10]);
                    acc[r][11] = fmaf(a, w2.w, acc[r][11]);
                }
            }
        }
        __syncthreads();
    }
    #pragma unroll
    for (int r = 0; r < 4; ++r) {
        int row = row0 + ty + 16 * r;
        if (row < M) {
            float* cp = &C[(size_t)row * 96 + tx * 12];
            *(float4*)(cp)     = make_float4(acc[r][0], acc[r][1], acc[r][2], acc[r][3]);
            *(float4*)(cp + 4) = make_float4(acc[r][4], acc[r][5], acc[r][6], acc[r][7]);
            *(float4*)(cp + 8) = make_float4(acc[r][8], acc[r][9], acc[r][10], acc[r][11]);
        }
    }
}

// ---------------- aggregate + bias + relu (float4 lanes) ----------------
#define QH (DH / 4)   // 24 float4 per node
__global__ void k_agg(const float4* __restrict__ ht4, const float* __restrict__ dis,
                      const int* __restrict__ rowptr, const int* __restrict__ esrc,
                      const float4* __restrict__ bias4, float4* __restrict__ hout4) {
    int gid = blockIdx.x * blockDim.x + threadIdx.x;
    if (gid >= NN * QH) return;
    int n = gid / QH;
    int q = gid - n * QH;
    int beg = rowptr[n], end = rowptr[n + 1];
    float dn = dis[n];
    float4 h0 = ht4[(size_t)n * QH + q];
    float4 acc = make_float4(dn * h0.x, dn * h0.y, dn * h0.z, dn * h0.w);
    for (int e = beg; e < end; ++e) {
        int s = esrc[e];
        float ds = dis[s];
        float4 v = ht4[(size_t)s * QH + q];
        acc.x = fmaf(ds, v.x, acc.x);
        acc.y = fmaf(ds, v.y, acc.y);
        acc.z = fmaf(ds, v.z, acc.z);
        acc.w = fmaf(ds, v.w, acc.w);
    }
    float4 b = bias4[q];
    float4 r;
    r.x = fmaxf(fmaf(dn, acc.x, b.x), 0.f);
    r.y = fmaxf(fmaf(dn, acc.y, b.y), 0.f);
    r.z = fmaxf(fmaf(dn, acc.z, b.z), 0.f);
    r.w = fmaxf(fmaf(dn, acc.w, b.w), 0.f);
    hout4[gid] = r;
}

// ---------------- mean-pool: node-parallel partial sums ----------------
#define PNODES 128
__global__ void k_pool_partial(const float* __restrict__ h, const int* __restrict__ batch,
                               float* __restrict__ pooled, int* __restrict__ gcnt) {
    __shared__ int sbatch[PNODES];
    const int n0 = blockIdx.x * PNODES;
    const int nend = min(n0 + PNODES, NN);
    const int cnt = nend - n0;
    const int f = threadIdx.x;   // 128 threads
    if (f < cnt) sbatch[f] = batch[n0 + f];
    __syncthreads();
    if (f < DH) {
        float acc = 0.f;
        int cur = sbatch[0];
        for (int i = 0; i < cnt; ++i) {
            int g = sbatch[i];
            if (g != cur) {
                atomicAdd(&pooled[cur * DH + f], acc);
                acc = 0.f; cur = g;
            }
            acc += h[(size_t)(n0 + i) * DH + f];
        }
        atomicAdd(&pooled[cur * DH + f], acc);
    } else if (f == DH) {
        int c = 0;
        int cur = sbatch[0];
        for (int i = 0; i < cnt; ++i) {
            int g = sbatch[i];
            if (g != cur) { atomicAdd(&gcnt[cur], c); c = 0; cur = g; }
            ++c;
        }
        atomicAdd(&gcnt[cur], c);
    }
}

__global__ void k_fc(const float* __restrict__ pooled, const int* __restrict__ gcnt,
                     const float* __restrict__ Wfc, const float* __restrict__ bfc,
                     float* __restrict__ out) {
    const int t = threadIdx.x;   // 128 threads: (g, c)
    if (t >= NG * DOUTC) return;
    const int g = t / DOUTC;
    const int c = t - g * DOUTC;
    float inv = 1.f / fmaxf((float)gcnt[g], 1.f);
    float acc = bfc[c];
    #pragma unroll 8
    for (int j = 0; j < DH; ++j)
        acc += pooled[g * DH + j] * inv * Wfc[j * DOUTC + c];
    out[g * DOUTC + c] = acc;
}

extern "C" void kernel_launch(void* const* d_in, const int* in_sizes, int n_in,
                              void* d_out, int out_size, void* d_ws, size_t ws_size,
                              hipStream_t stream) {
    const float* x   = (const float*)d_in[0];
    const float* W1  = (const float*)d_in[1];
    const float* b1  = (const float*)d_in[2];
    const float* W2  = (const float*)d_in[3];
    const float* b2  = (const float*)d_in[4];
    const float* Wfc = (const float*)d_in[5];
    const float* bfc = (const float*)d_in[6];
    const int* src   = (const int*)d_in[7];
    const int* dst   = (const int*)d_in[8];
    const int* batch = (const int*)d_in[9];
    float* out = (float*)d_out;

    // workspace layout
    float* ht    = (float*)d_ws;              // NN*DH
    float* hbuf  = ht + (size_t)NN * DH;      // NN*DH
    float* dis   = hbuf + (size_t)NN * DH;    // NN
    float* pooled= dis + NN;                  // NG*DH
    int* cnt     = (int*)(pooled + NG * DH);  // NN
    int* fill    = cnt + NN;                  // NN
    int* gcnt    = fill + NN;                 // NG
    int* rowptr  = gcnt + NG;                 // NN+1
    int* esrc    = rowptr + NN + 2;           // NE

    const int TB = 256;
    // CSR build + degrees + zero-init of pooled/gcnt
    k_init<<<(NN + TB - 1) / TB, TB, 0, stream>>>(cnt, fill, pooled, gcnt);
    k_hist<<<(NE + TB - 1) / TB, TB, 0, stream>>>(dst, cnt);
    k_dis<<<(NN + TB - 1) / TB, TB, 0, stream>>>(cnt, dis);
    k_scan<<<1, 1024, 0, stream>>>(cnt, rowptr);
    k_scatter<<<(NE + TB - 1) / TB, TB, 0, stream>>>(src, dst, rowptr, fill, esrc);

    // layer 1
    k_gemm<DIN, 60><<<(NN + 63) / 64, 128, 0, stream>>>(x, W1, ht, NN);
    k_agg<<<(NN * QH + TB - 1) / TB, TB, 0, stream>>>(
        (const float4*)ht, dis, rowptr, esrc, (const float4*)b1, (float4*)hbuf);
    // layer 2
    k_gemm<DH, 48><<<(NN + 63) / 64, 128, 0, stream>>>(hbuf, W2, ht, NN);
    k_agg<<<(NN * QH + TB - 1) / TB, TB, 0, stream>>>(
        (const float4*)ht, dis, rowptr, esrc, (const float4*)b2, (float4*)hbuf);
    // pool + fc
    k_pool_partial<<<(NN + PNODES - 1) / PNODES, 128, 0, stream>>>(hbuf, batch, pooled, gcnt);
    k_fc<<<1, 128, 0, stream>>>(pooled, gcnt, Wfc, bfc, out);
}

// Round 5
// 473.755 us; speedup vs baseline: 1.7909x; 1.0915x over previous
//
#include <hip/hip_runtime.h>
#include <hip/hip_bf16.h>

#define NN 50000
#define NE 800000
#define DIN 300
#define KP1 320
#define DH 96
#define DOUTC 2
#define NG 64

typedef __attribute__((ext_vector_type(8))) short bf16x8;
typedef __attribute__((ext_vector_type(4))) float f32x4;

__device__ inline unsigned short f2bf(float f) {
    unsigned int u = __float_as_uint(f);
    unsigned int r = (u + 0x7fffu + ((u >> 16) & 1u)) >> 16;
    return (unsigned short)r;
}

// ---------------- CSR build ----------------
__global__ void k_init(int* cnt, int* fill, float* pooled, int* gcnt) {
    int i = blockIdx.x * blockDim.x + threadIdx.x;
    if (i < NN) { cnt[i] = 0; fill[i] = 0; }
    if (i < NG * DH) pooled[i] = 0.f;
    if (i < NG) gcnt[i] = 0;
}

__global__ void k_hist(const int* __restrict__ dst, int* cnt) {
    int e = blockIdx.x * blockDim.x + threadIdx.x;
    if (e < NE) atomicAdd(&cnt[dst[e]], 1);
}

__global__ void k_dis(const int* __restrict__ cnt, float* dis) {
    int i = blockIdx.x * blockDim.x + threadIdx.x;
    if (i < NN) dis[i] = rsqrtf(1.0f + (float)cnt[i]);
}

__global__ void k_scan(const int* __restrict__ cnt, int* rowptr) {
    __shared__ int part[1024];
    const int t = threadIdx.x;
    const int C = (NN + 1023) / 1024;
    int s0 = t * C, s1 = min(s0 + C, NN);
    if (s0 > NN) s0 = NN;
    if (s1 < s0) s1 = s0;
    int sum = 0;
    for (int i = s0; i < s1; ++i) sum += cnt[i];
    part[t] = sum;
    __syncthreads();
    for (int off = 1; off < 1024; off <<= 1) {
        int v = (t >= off) ? part[t - off] : 0;
        __syncthreads();
        part[t] += v;
        __syncthreads();
    }
    int run = (t == 0) ? 0 : part[t - 1];
    for (int i = s0; i < s1; ++i) { rowptr[i] = run; run += cnt[i]; }
    if (t == 1023) rowptr[NN] = run;
}

__global__ void k_scatter(const int* __restrict__ src, const int* __restrict__ dst,
                          const int* __restrict__ rowptr, int* fill, int* esrc) {
    int e = blockIdx.x * blockDim.x + threadIdx.x;
    if (e < NE) {
        int d = dst[e];
        int pos = rowptr[d] + atomicAdd(&fill[d], 1);
        esrc[pos] = src[e];
    }
}

// ---------------- W -> W^T bf16 (zero-padded K) ----------------
__global__ void k_wt(const float* __restrict__ W, unsigned short* __restrict__ WT,
                     int K, int KPAD) {
    int i = blockIdx.x * blockDim.x + threadIdx.x;   // over DH*KPAD
    if (i >= DH * KPAD) return;
    int j = i / KPAD, k = i - j * KPAD;
    WT[i] = (k < K) ? f2bf(W[(size_t)k * DH + j]) : (unsigned short)0;
}

// ---------------- GEMM1: C[NN][96] = x[NN][300] @ W1, bf16 MFMA ----------------
// 256 thr = 4 waves; wave tile 16 rows x 96 cols, 6 acc frags; no LDS.
// A-frag: A[m=lane&15][k=quad*8+j] (fp32->bf16 on the fly, masked past K=300).
// B-frag: WT[n=lane&15 + 16t][k=quad*8+j] (pre-transposed, zero-padded to 320).
__global__ __launch_bounds__(256) void k_gemm1(const float* __restrict__ A,
        const unsigned short* __restrict__ WT, float* __restrict__ C) {
    const int tid = threadIdx.x;
    const int wv = tid >> 6;
    const int lane = tid & 63;
    const int m = lane & 15;
    const int quad = lane >> 4;
    const int row = blockIdx.x * 64 + wv * 16 + m;
    const int arow = row < NN ? row : NN - 1;
    const float* ap = A + (size_t)arow * DIN + quad * 8;
    const unsigned short* wp = WT + (size_t)m * KP1 + quad * 8;
    f32x4 acc[6];
    #pragma unroll
    for (int t = 0; t < 6; ++t) acc[t] = (f32x4){0.f, 0.f, 0.f, 0.f};
    #pragma unroll
    for (int k0 = 0; k0 < KP1; k0 += 32) {
        const int kb = k0 + quad * 8;
        float4 a0 = *(const float4*)(ap + k0);
        float4 a1 = *(const float4*)(ap + k0 + 4);
        float va[8] = {a0.x, a0.y, a0.z, a0.w, a1.x, a1.y, a1.z, a1.w};
        bf16x8 af;
        #pragma unroll
        for (int j = 0; j < 8; ++j)
            af[j] = (kb + j < DIN) ? (short)f2bf(va[j]) : (short)0;
        #pragma unroll
        for (int t = 0; t < 6; ++t) {
            bf16x8 bf = *(const bf16x8*)(wp + (size_t)t * 16 * KP1 + k0);
            acc[t] = __builtin_amdgcn_mfma_f32_16x16x32_bf16(af, bf, acc[t], 0, 0, 0);
        }
    }
    const int rbase = blockIdx.x * 64 + wv * 16 + quad * 4;
    #pragma unroll
    for (int r = 0; r < 4; ++r) {
        int rr = rbase + r;
        if (rr < NN) {
            float* cp = C + (size_t)rr * DH + m;
            #pragma unroll
            for (int t = 0; t < 6; ++t) cp[t * 16] = acc[t][r];
        }
    }
}

// ---------------- GEMM2: C[NN][96] = h1b[NN][96](bf16) @ W2 ----------------
__global__ __launch_bounds__(256) void k_gemm2(const unsigned short* __restrict__ Ab,
        const unsigned short* __restrict__ WT, float* __restrict__ C) {
    const int tid = threadIdx.x;
    const int wv = tid >> 6;
    const int lane = tid & 63;
    const int m = lane & 15;
    const int quad = lane >> 4;
    const int row = blockIdx.x * 64 + wv * 16 + m;
    const int arow = row < NN ? row : NN - 1;
    const unsigned short* ap = Ab + (size_t)arow * DH + quad * 8;
    const unsigned short* wp = WT + (size_t)m * DH + quad * 8;
    f32x4 acc[6];
    #pragma unroll
    for (int t = 0; t < 6; ++t) acc[t] = (f32x4){0.f, 0.f, 0.f, 0.f};
    #pragma unroll
    for (int k0 = 0; k0 < DH; k0 += 32) {
        bf16x8 af = *(const bf16x8*)(ap + k0);
        #pragma unroll
        for (int t = 0; t < 6; ++t) {
            bf16x8 bf = *(const bf16x8*)(wp + (size_t)t * 16 * DH + k0);
            acc[t] = __builtin_amdgcn_mfma_f32_16x16x32_bf16(af, bf, acc[t], 0, 0, 0);
        }
    }
    const int rbase = blockIdx.x * 64 + wv * 16 + quad * 4;
    #pragma unroll
    for (int r = 0; r < 4; ++r) {
        int rr = rbase + r;
        if (rr < NN) {
            float* cp = C + (size_t)rr * DH + m;
            #pragma unroll
            for (int t = 0; t < 6; ++t) cp[t * 16] = acc[t][r];
        }
    }
}

// ---------------- aggregate + bias + relu (float4 lanes) ----------------
#define QH (DH / 4)   // 24 float4 per node
template <bool BFOUT>
__global__ void k_agg(const float4* __restrict__ ht4, const float* __restrict__ dis,
                      const int* __restrict__ rowptr, const int* __restrict__ esrc,
                      const float4* __restrict__ bias4, float4* __restrict__ fout,
                      ushort4* __restrict__ bout) {
    int gid = blockIdx.x * blockDim.x + threadIdx.x;
    if (gid >= NN * QH) return;
    int n = gid / QH;
    int q = gid - n * QH;
    int beg = rowptr[n], end = rowptr[n + 1];
    float dn = dis[n];
    float4 h0 = ht4[(size_t)n * QH + q];
    float4 acc = make_float4(dn * h0.x, dn * h0.y, dn * h0.z, dn * h0.w);
    for (int e = beg; e < end; ++e) {
        int s = esrc[e];
        float ds = dis[s];
        float4 v = ht4[(size_t)s * QH + q];
        acc.x = fmaf(ds, v.x, acc.x);
        acc.y = fmaf(ds, v.y, acc.y);
        acc.z = fmaf(ds, v.z, acc.z);
        acc.w = fmaf(ds, v.w, acc.w);
    }
    float4 b = bias4[q];
    float4 r;
    r.x = fmaxf(fmaf(dn, acc.x, b.x), 0.f);
    r.y = fmaxf(fmaf(dn, acc.y, b.y), 0.f);
    r.z = fmaxf(fmaf(dn, acc.z, b.z), 0.f);
    r.w = fmaxf(fmaf(dn, acc.w, b.w), 0.f);
    if (BFOUT) {
        ushort4 o;
        o.x = f2bf(r.x); o.y = f2bf(r.y); o.z = f2bf(r.z); o.w = f2bf(r.w);
        bout[gid] = o;
    } else {
        fout[gid] = r;
    }
}

// ---------------- mean-pool: node-parallel partial sums ----------------
#define PNODES 128
__global__ void k_pool_partial(const float* __restrict__ h, const int* __restrict__ batch,
                               float* __restrict__ pooled, int* __restrict__ gcnt) {
    __shared__ int sbatch[PNODES];
    const int n0 = blockIdx.x * PNODES;
    const int nend = min(n0 + PNODES, NN);
    const int cnt = nend - n0;
    const int f = threadIdx.x;   // 128 threads
    if (f < cnt) sbatch[f] = batch[n0 + f];
    __syncthreads();
    if (f < DH) {
        float acc = 0.f;
        int cur = sbatch[0];
        for (int i = 0; i < cnt; ++i) {
            int g = sbatch[i];
            if (g != cur) {
                atomicAdd(&pooled[cur * DH + f], acc);
                acc = 0.f; cur = g;
            }
            acc += h[(size_t)(n0 + i) * DH + f];
        }
        atomicAdd(&pooled[cur * DH + f], acc);
    } else if (f == DH) {
        int c = 0;
        int cur = sbatch[0];
        for (int i = 0; i < cnt; ++i) {
            int g = sbatch[i];
            if (g != cur) { atomicAdd(&gcnt[cur], c); c = 0; cur = g; }
            ++c;
        }
        atomicAdd(&gcnt[cur], c);
    }
}

__global__ void k_fc(const float* __restrict__ pooled, const int* __restrict__ gcnt,
                     const float* __restrict__ Wfc, const float* __restrict__ bfc,
                     float* __restrict__ out) {
    const int t = threadIdx.x;   // 128 threads: (g, c)
    if (t >= NG * DOUTC) return;
    const int g = t / DOUTC;
    const int c = t - g * DOUTC;
    float inv = 1.f / fmaxf((float)gcnt[g], 1.f);
    float acc = bfc[c];
    #pragma unroll 8
    for (int j = 0; j < DH; ++j)
        acc += pooled[g * DH + j] * inv * Wfc[j * DOUTC + c];
    out[g * DOUTC + c] = acc;
}

extern "C" void kernel_launch(void* const* d_in, const int* in_sizes, int n_in,
                              void* d_out, int out_size, void* d_ws, size_t ws_size,
                              hipStream_t stream) {
    const float* x   = (const float*)d_in[0];
    const float* W1  = (const float*)d_in[1];
    const float* b1  = (const float*)d_in[2];
    const float* W2  = (const float*)d_in[3];
    const float* b2  = (const float*)d_in[4];
    const float* Wfc = (const float*)d_in[5];
    const float* bfc = (const float*)d_in[6];
    const int* src   = (const int*)d_in[7];
    const int* dst   = (const int*)d_in[8];
    const int* batch = (const int*)d_in[9];
    float* out = (float*)d_out;

    // workspace layout (~42.5 MB). h1b (bf16 layer-1 activations) overlays hbuf:
    // gemm2 consumes h1b before agg2 writes hbuf (stream-ordered, safe).
    float* ht    = (float*)d_ws;              // NN*DH f32 (both GEMM outputs)
    float* hbuf  = ht + (size_t)NN * DH;      // NN*DH f32 (agg2 out)
    unsigned short* h1b = (unsigned short*)hbuf; // NN*DH bf16 (agg1 out, overlay)
    float* dis   = hbuf + (size_t)NN * DH;    // NN
    float* pooled= dis + NN;                  // NG*DH
    int* cnt     = (int*)(pooled + NG * DH);  // NN
    int* fill    = cnt + NN;                  // NN
    int* gcnt    = fill + NN;                 // NG
    int* rowptr  = gcnt + NG;                 // NN+1
    int* esrc    = rowptr + NN + 2;           // NE
    unsigned short* wt1 = (unsigned short*)(esrc + NE);  // DH*KP1
    unsigned short* wt2 = wt1 + DH * KP1;                // DH*DH

    const int TB = 256;
    // CSR build + degrees + zero-init + weight transposes
    k_init<<<(NN + TB - 1) / TB, TB, 0, stream>>>(cnt, fill, pooled, gcnt);
    k_hist<<<(NE + TB - 1) / TB, TB, 0, stream>>>(dst, cnt);
    k_dis<<<(NN + TB - 1) / TB, TB, 0, stream>>>(cnt, dis);
    k_scan<<<1, 1024, 0, stream>>>(cnt, rowptr);
    k_scatter<<<(NE + TB - 1) / TB, TB, 0, stream>>>(src, dst, rowptr, fill, esrc);
    k_wt<<<(DH * KP1 + TB - 1) / TB, TB, 0, stream>>>(W1, wt1, DIN, KP1);
    k_wt<<<(DH * DH + TB - 1) / TB, TB, 0, stream>>>(W2, wt2, DH, DH);

    // layer 1: MFMA GEMM (fp32->bf16 on the fly), agg writes bf16
    k_gemm1<<<(NN + 63) / 64, 256, 0, stream>>>(x, wt1, ht);
    k_agg<true><<<(NN * QH + TB - 1) / TB, TB, 0, stream>>>(
        (const float4*)ht, dis, rowptr, esrc, (const float4*)b1,
        nullptr, (ushort4*)h1b);
    // layer 2: MFMA GEMM (bf16 A), agg writes fp32
    k_gemm2<<<(NN + 63) / 64, 256, 0, stream>>>(h1b, wt2, ht);
    k_agg<false><<<(NN * QH + TB - 1) / TB, TB, 0, stream>>>(
        (const float4*)ht, dis, rowptr, esrc, (const float4*)b2,
        (float4*)hbuf, nullptr);
    // pool + fc
    k_pool_partial<<<(NN + PNODES - 1) / PNODES, 128, 0, stream>>>(hbuf, batch, pooled, gcnt);
    k_fc<<<1, 128, 0, stream>>>(pooled, gcnt, Wfc, bfc, out);
}

// Round 6
// 399.833 us; speedup vs baseline: 2.1220x; 1.1849x over previous
//
#include <hip/hip_runtime.h>
#include <hip/hip_bf16.h>

#define NN 50000
#define NE 800000
#define DIN 300
#define KP1 320
#define DH 96
#define DOUTC 2
#define NG 64

#define SCB 256
#define NSB ((NN + SCB - 1) / SCB)   // 196 scan blocks

typedef __attribute__((ext_vector_type(8))) short bf16x8;
typedef __attribute__((ext_vector_type(4))) float f32x4;

__device__ inline unsigned short f2bf(float f) {
    unsigned int u = __float_as_uint(f);
    unsigned int r = (u + 0x7fffu + ((u >> 16) & 1u)) >> 16;
    return (unsigned short)r;
}

// ---------------- CSR build ----------------
__global__ void k_init(int* cnt, int* fill, float* pooled, int* gcnt) {
    int i = blockIdx.x * blockDim.x + threadIdx.x;
    if (i < NN) { cnt[i] = 0; fill[i] = 0; }
    if (i < NG * DH) pooled[i] = 0.f;
    if (i < NG) gcnt[i] = 0;
}

__global__ void k_hist(const int* __restrict__ dst, int* cnt) {
    int e = blockIdx.x * blockDim.x + threadIdx.x;
    if (e < NE) atomicAdd(&cnt[dst[e]], 1);
}

// phase 1: per-block LDS scan; writes exclusive prefix, block total, and dis
__global__ void k_scan1(const int* __restrict__ cnt, int* __restrict__ rowptr,
                        int* __restrict__ bsum, float* __restrict__ dis) {
    __shared__ int s[SCB];
    const int t = threadIdx.x;
    const int i = blockIdx.x * SCB + t;
    int v = (i < NN) ? cnt[i] : 0;
    if (i < NN) dis[i] = rsqrtf(1.0f + (float)v);
    s[t] = v;
    __syncthreads();
    #pragma unroll
    for (int off = 1; off < SCB; off <<= 1) {
        int u = (t >= off) ? s[t - off] : 0;
        __syncthreads();
        s[t] += u;
        __syncthreads();
    }
    if (i < NN) rowptr[i] = s[t] - v;
    if (t == SCB - 1) bsum[blockIdx.x] = s[t];
}

// phase 2: scan the 196 block totals (one block)
__global__ void k_scan2(int* __restrict__ bsum, int* __restrict__ rowptr) {
    __shared__ int s[256];
    const int t = threadIdx.x;
    int v = (t < NSB) ? bsum[t] : 0;
    s[t] = v;
    __syncthreads();
    #pragma unroll
    for (int off = 1; off < 256; off <<= 1) {
        int u = (t >= off) ? s[t - off] : 0;
        __syncthreads();
        s[t] += u;
        __syncthreads();
    }
    if (t < NSB) bsum[t] = s[t] - v;
    if (t == 255) rowptr[NN] = s[t];
}

// phase 3: add block offsets
__global__ void k_scan3(int* __restrict__ rowptr, const int* __restrict__ bsum) {
    int i = blockIdx.x * SCB + threadIdx.x;
    if (i < NN) rowptr[i] += bsum[blockIdx.x];
}

__global__ void k_scatter(const int* __restrict__ src, const int* __restrict__ dst,
                          const int* __restrict__ rowptr, int* fill, int* esrc) {
    int e = blockIdx.x * blockDim.x + threadIdx.x;
    if (e < NE) {
        int d = dst[e];
        int pos = rowptr[d] + atomicAdd(&fill[d], 1);
        esrc[pos] = src[e];
    }
}

// ---------------- W -> W^T bf16 (zero-padded K) ----------------
__global__ void k_wt(const float* __restrict__ W, unsigned short* __restrict__ WT,
                     int K, int KPAD) {
    int i = blockIdx.x * blockDim.x + threadIdx.x;   // over DH*KPAD
    if (i >= DH * KPAD) return;
    int j = i / KPAD, k = i - j * KPAD;
    WT[i] = (k < K) ? f2bf(W[(size_t)k * DH + j]) : (unsigned short)0;
}

// ---------------- GEMM1: C[NN][96] = x[NN][300] @ W1, bf16 MFMA ----------------
__global__ __launch_bounds__(256) void k_gemm1(const float* __restrict__ A,
        const unsigned short* __restrict__ WT, float* __restrict__ C) {
    const int tid = threadIdx.x;
    const int wv = tid >> 6;
    const int lane = tid & 63;
    const int m = lane & 15;
    const int quad = lane >> 4;
    const int row = blockIdx.x * 64 + wv * 16 + m;
    const int arow = row < NN ? row : NN - 1;
    const float* ap = A + (size_t)arow * DIN + quad * 8;
    const unsigned short* wp = WT + (size_t)m * KP1 + quad * 8;
    f32x4 acc[6];
    #pragma unroll
    for (int t = 0; t < 6; ++t) acc[t] = (f32x4){0.f, 0.f, 0.f, 0.f};
    #pragma unroll
    for (int k0 = 0; k0 < KP1; k0 += 32) {
        const int kb = k0 + quad * 8;
        float4 a0 = *(const float4*)(ap + k0);
        float4 a1 = *(const float4*)(ap + k0 + 4);
        float va[8] = {a0.x, a0.y, a0.z, a0.w, a1.x, a1.y, a1.z, a1.w};
        bf16x8 af;
        #pragma unroll
        for (int j = 0; j < 8; ++j)
            af[j] = (kb + j < DIN) ? (short)f2bf(va[j]) : (short)0;
        #pragma unroll
        for (int t = 0; t < 6; ++t) {
            bf16x8 bf = *(const bf16x8*)(wp + (size_t)t * 16 * KP1 + k0);
            acc[t] = __builtin_amdgcn_mfma_f32_16x16x32_bf16(af, bf, acc[t], 0, 0, 0);
        }
    }
    const int rbase = blockIdx.x * 64 + wv * 16 + quad * 4;
    #pragma unroll
    for (int r = 0; r < 4; ++r) {
        int rr = rbase + r;
        if (rr < NN) {
            float* cp = C + (size_t)rr * DH + m;
            #pragma unroll
            for (int t = 0; t < 6; ++t) cp[t * 16] = acc[t][r];
        }
    }
}

// ---------------- GEMM2: C[NN][96] = h1b[NN][96](bf16) @ W2 ----------------
__global__ __launch_bounds__(256) void k_gemm2(const unsigned short* __restrict__ Ab,
        const unsigned short* __restrict__ WT, float* __restrict__ C) {
    const int tid = threadIdx.x;
    const int wv = tid >> 6;
    const int lane = tid & 63;
    const int m = lane & 15;
    const int quad = lane >> 4;
    const int row = blockIdx.x * 64 + wv * 16 + m;
    const int arow = row < NN ? row : NN - 1;
    const unsigned short* ap = Ab + (size_t)arow * DH + quad * 8;
    const unsigned short* wp = WT + (size_t)m * DH + quad * 8;
    f32x4 acc[6];
    #pragma unroll
    for (int t = 0; t < 6; ++t) acc[t] = (f32x4){0.f, 0.f, 0.f, 0.f};
    #pragma unroll
    for (int k0 = 0; k0 < DH; k0 += 32) {
        bf16x8 af = *(const bf16x8*)(ap + k0);
        #pragma unroll
        for (int t = 0; t < 6; ++t) {
            bf16x8 bf = *(const bf16x8*)(wp + (size_t)t * 16 * DH + k0);
            acc[t] = __builtin_amdgcn_mfma_f32_16x16x32_bf16(af, bf, acc[t], 0, 0, 0);
        }
    }
    const int rbase = blockIdx.x * 64 + wv * 16 + quad * 4;
    #pragma unroll
    for (int r = 0; r < 4; ++r) {
        int rr = rbase + r;
        if (rr < NN) {
            float* cp = C + (size_t)rr * DH + m;
            #pragma unroll
            for (int t = 0; t < 6; ++t) cp[t * 16] = acc[t][r];
        }
    }
}

// ---------------- aggregate + bias + relu (float4 lanes) ----------------
#define QH (DH / 4)   // 24 float4 per node
template <bool BFOUT>
__global__ void k_agg(const float4* __restrict__ ht4, const float* __restrict__ dis,
                      const int* __restrict__ rowptr, const int* __restrict__ esrc,
                      const float4* __restrict__ bias4, float4* __restrict__ fout,
                      ushort4* __restrict__ bout) {
    int gid = blockIdx.x * blockDim.x + threadIdx.x;
    if (gid >= NN * QH) return;
    int n = gid / QH;
    int q = gid - n * QH;
    int beg = rowptr[n], end = rowptr[n + 1];
    float dn = dis[n];
    float4 h0 = ht4[(size_t)n * QH + q];
    float4 acc = make_float4(dn * h0.x, dn * h0.y, dn * h0.z, dn * h0.w);
    for (int e = beg; e < end; ++e) {
        int s = esrc[e];
        float ds = dis[s];
        float4 v = ht4[(size_t)s * QH + q];
        acc.x = fmaf(ds, v.x, acc.x);
        acc.y = fmaf(ds, v.y, acc.y);
        acc.z = fmaf(ds, v.z, acc.z);
        acc.w = fmaf(ds, v.w, acc.w);
    }
    float4 b = bias4[q];
    float4 r;
    r.x = fmaxf(fmaf(dn, acc.x, b.x), 0.f);
    r.y = fmaxf(fmaf(dn, acc.y, b.y), 0.f);
    r.z = fmaxf(fmaf(dn, acc.z, b.z), 0.f);
    r.w = fmaxf(fmaf(dn, acc.w, b.w), 0.f);
    if (BFOUT) {
        ushort4 o;
        o.x = f2bf(r.x); o.y = f2bf(r.y); o.z = f2bf(r.z); o.w = f2bf(r.w);
        bout[gid] = o;
    } else {
        fout[gid] = r;
    }
}

// ---------------- mean-pool: node-parallel partial sums ----------------
#define PNODES 128
__global__ void k_pool_partial(const float* __restrict__ h, const int* __restrict__ batch,
                               float* __restrict__ pooled, int* __restrict__ gcnt) {
    __shared__ int sbatch[PNODES];
    const int n0 = blockIdx.x * PNODES;
    const int nend = min(n0 + PNODES, NN);
    const int cnt = nend - n0;
    const int f = threadIdx.x;   // 128 threads
    if (f < cnt) sbatch[f] = batch[n0 + f];
    __syncthreads();
    if (f < DH) {
        float acc = 0.f;
        int cur = sbatch[0];
        for (int i = 0; i < cnt; ++i) {
            int g = sbatch[i];
            if (g != cur) {
                atomicAdd(&pooled[cur * DH + f], acc);
                acc = 0.f; cur = g;
            }
            acc += h[(size_t)(n0 + i) * DH + f];
        }
        atomicAdd(&pooled[cur * DH + f], acc);
    } else if (f == DH) {
        int c = 0;
        int cur = sbatch[0];
        for (int i = 0; i < cnt; ++i) {
            int g = sbatch[i];
            if (g != cur) { atomicAdd(&gcnt[cur], c); c = 0; cur = g; }
            ++c;
        }
        atomicAdd(&gcnt[cur], c);
    }
}

__global__ void k_fc(const float* __restrict__ pooled, const int* __restrict__ gcnt,
                     const float* __restrict__ Wfc, const float* __restrict__ bfc,
                     float* __restrict__ out) {
    const int t = threadIdx.x;   // 128 threads: (g, c)
    if (t >= NG * DOUTC) return;
    const int g = t / DOUTC;
    const int c = t - g * DOUTC;
    float inv = 1.f / fmaxf((float)gcnt[g], 1.f);
    float acc = bfc[c];
    #pragma unroll 8
    for (int j = 0; j < DH; ++j)
        acc += pooled[g * DH + j] * inv * Wfc[j * DOUTC + c];
    out[g * DOUTC + c] = acc;
}

extern "C" void kernel_launch(void* const* d_in, const int* in_sizes, int n_in,
                              void* d_out, int out_size, void* d_ws, size_t ws_size,
                              hipStream_t stream) {
    const float* x   = (const float*)d_in[0];
    const float* W1  = (const float*)d_in[1];
    const float* b1  = (const float*)d_in[2];
    const float* W2  = (const float*)d_in[3];
    const float* b2  = (const float*)d_in[4];
    const float* Wfc = (const float*)d_in[5];
    const float* bfc = (const float*)d_in[6];
    const int* src   = (const int*)d_in[7];
    const int* dst   = (const int*)d_in[8];
    const int* batch = (const int*)d_in[9];
    float* out = (float*)d_out;

    // workspace layout (~42.5 MB). h1b (bf16 layer-1 activations) overlays hbuf.
    float* ht    = (float*)d_ws;              // NN*DH f32 (both GEMM outputs)
    float* hbuf  = ht + (size_t)NN * DH;      // NN*DH f32 (agg2 out)
    unsigned short* h1b = (unsigned short*)hbuf; // NN*DH bf16 (agg1 out, overlay)
    float* dis   = hbuf + (size_t)NN * DH;    // NN
    float* pooled= dis + NN;                  // NG*DH
    int* cnt     = (int*)(pooled + NG * DH);  // NN
    int* fill    = cnt + NN;                  // NN
    int* gcnt    = fill + NN;                 // NG
    int* rowptr  = gcnt + NG;                 // NN+1
    int* bsum    = rowptr + NN + 2;           // NSB
    int* esrc    = bsum + NSB;                // NE
    unsigned short* wt1 = (unsigned short*)(esrc + NE);  // DH*KP1
    unsigned short* wt2 = wt1 + DH * KP1;                // DH*DH

    const int TB = 256;
    // CSR build + degrees + zero-init + weight transposes
    k_init<<<(NN + TB - 1) / TB, TB, 0, stream>>>(cnt, fill, pooled, gcnt);
    k_hist<<<(NE + TB - 1) / TB, TB, 0, stream>>>(dst, cnt);
    k_scan1<<<NSB, SCB, 0, stream>>>(cnt, rowptr, bsum, dis);
    k_scan2<<<1, 256, 0, stream>>>(bsum, rowptr);
    k_scan3<<<NSB, SCB, 0, stream>>>(rowptr, bsum);
    k_scatter<<<(NE + TB - 1) / TB, TB, 0, stream>>>(src, dst, rowptr, fill, esrc);
    k_wt<<<(DH * KP1 + TB - 1) / TB, TB, 0, stream>>>(W1, wt1, DIN, KP1);
    k_wt<<<(DH * DH + TB - 1) / TB, TB, 0, stream>>>(W2, wt2, DH, DH);

    // layer 1: MFMA GEMM (fp32->bf16 on the fly), agg writes bf16
    k_gemm1<<<(NN + 63) / 64, 256, 0, stream>>>(x, wt1, ht);
    k_agg<true><<<(NN * QH + TB - 1) / TB, TB, 0, stream>>>(
        (const float4*)ht, dis, rowptr, esrc, (const float4*)b1,
        nullptr, (ushort4*)h1b);
    // layer 2: MFMA GEMM (bf16 A), agg writes fp32
    k_gemm2<<<(NN + 63) / 64, 256, 0, stream>>>(h1b, wt2, ht);
    k_agg<false><<<(NN * QH + TB - 1) / TB, TB, 0, stream>>>(
        (const float4*)ht, dis, rowptr, esrc, (const float4*)b2,
        (float4*)hbuf, nullptr);
    // pool + fc
    k_pool_partial<<<(NN + PNODES - 1) / PNODES, 128, 0, stream>>>(hbuf, batch, pooled, gcnt);
    k_fc<<<1, 128, 0, stream>>>(pooled, gcnt, Wfc, bfc, out);
}

// Round 9
// 369.554 us; speedup vs baseline: 2.2958x; 1.0819x over previous
//
#include <hip/hip_runtime.h>
#include <hip/hip_bf16.h>

#define NN 50000
#define NE 800000
#define DIN 300
#define KP1 320
#define DH 96
#define DOUTC 2
#define NG 64

#define SCB 256
#define NSB ((NN + SCB - 1) / SCB)   // 196 scan blocks

typedef __attribute__((ext_vector_type(8))) short bf16x8;
typedef __attribute__((ext_vector_type(4))) float f32x4;

__device__ inline unsigned short f2bf(float f) {
    unsigned int u = __float_as_uint(f);
    unsigned int r = (u + 0x7fffu + ((u >> 16) & 1u)) >> 16;
    return (unsigned short)r;
}

// ---------------- CSR build ----------------
__global__ void k_init(int* cnt, int* fill, float* pooled, int* gcnt) {
    int i = blockIdx.x * blockDim.x + threadIdx.x;
    if (i < NN) { cnt[i] = 0; fill[i] = 0; }
    if (i < NG * DH) pooled[i] = 0.f;
    if (i < NG) gcnt[i] = 0;
}

__global__ void k_hist(const int* __restrict__ dst, int* cnt) {
    int e = blockIdx.x * blockDim.x + threadIdx.x;
    if (e < NE) atomicAdd(&cnt[dst[e]], 1);
}

__global__ void k_scan1(const int* __restrict__ cnt, int* __restrict__ rowptr,
                        int* __restrict__ bsum, float* __restrict__ dis) {
    __shared__ int s[SCB];
    const int t = threadIdx.x;
    const int i = blockIdx.x * SCB + t;
    int v = (i < NN) ? cnt[i] : 0;
    if (i < NN) dis[i] = rsqrtf(1.0f + (float)v);
    s[t] = v;
    __syncthreads();
    #pragma unroll
    for (int off = 1; off < SCB; off <<= 1) {
        int u = (t >= off) ? s[t - off] : 0;
        __syncthreads();
        s[t] += u;
        __syncthreads();
    }
    if (i < NN) rowptr[i] = s[t] - v;
    if (t == SCB - 1) bsum[blockIdx.x] = s[t];
}

__global__ void k_scan2(int* __restrict__ bsum, int* __restrict__ rowptr) {
    __shared__ int s[256];
    const int t = threadIdx.x;
    int v = (t < NSB) ? bsum[t] : 0;
    s[t] = v;
    __syncthreads();
    #pragma unroll
    for (int off = 1; off < 256; off <<= 1) {
        int u = (t >= off) ? s[t - off] : 0;
        __syncthreads();
        s[t] += u;
        __syncthreads();
    }
    if (t < NSB) bsum[t] = s[t] - v;
    if (t == 255) rowptr[NN] = s[t];
}

__global__ void k_scan3(int* __restrict__ rowptr, const int* __restrict__ bsum) {
    int i = blockIdx.x * SCB + threadIdx.x;
    if (i < NN) rowptr[i] += bsum[blockIdx.x];
}

__global__ void k_scatter(const int* __restrict__ src, const int* __restrict__ dst,
                          const int* __restrict__ rowptr, int* fill, int* esrc) {
    int e = blockIdx.x * blockDim.x + threadIdx.x;
    if (e < NE) {
        int d = dst[e];
        int pos = rowptr[d] + atomicAdd(&fill[d], 1);
        esrc[pos] = src[e];
    }
}

// ---------------- W -> W^T bf16 (zero-padded K) ----------------
__global__ void k_wt(const float* __restrict__ W, unsigned short* __restrict__ WT,
                     int K, int KPAD) {
    int i = blockIdx.x * blockDim.x + threadIdx.x;
    if (i >= DH * KPAD) return;
    int j = i / KPAD, k = i - j * KPAD;
    WT[i] = (k < K) ? f2bf(W[(size_t)k * DH + j]) : (unsigned short)0;
}

// ---------------- GEMM1: C[NN][96](f32) = x[NN][300] @ W1 ----------------
// Depth-4 ring, prefetch distance 3 (3 mod 4 != 0 -> write slot never equals
// consume slot; the depth-3 version in R7/R8 clobbered the slot it was about
// to read -- computed a garbage GEMM that mean-pool masked to 4.9e-3).
__global__ __launch_bounds__(256) void k_gemm1(const float* __restrict__ A,
        const unsigned short* __restrict__ WT, float* __restrict__ C) {
    const int tid = threadIdx.x;
    const int wv = tid >> 6;
    const int lane = tid & 63;
    const int m = lane & 15;
    const int quad = lane >> 4;
    const int row = blockIdx.x * 64 + wv * 16 + m;
    const int arow = row < NN ? row : NN - 1;
    const float* ap = A + (size_t)arow * DIN + quad * 8;
    const unsigned short* wp = WT + (size_t)m * KP1 + quad * 8;
    const float4 z4 = make_float4(0.f, 0.f, 0.f, 0.f);
    f32x4 acc[6];
    #pragma unroll
    for (int t = 0; t < 6; ++t) acc[t] = (f32x4){0.f, 0.f, 0.f, 0.f};

    float4 pa[4][2];
    #pragma unroll
    for (int i = 0; i < 3; ++i) {
        int kb = i * 32 + quad * 8;
        pa[i][0] = (kb + 4 <= DIN) ? *(const float4*)(ap + i * 32) : z4;
        pa[i][1] = (kb + 8 <= DIN) ? *(const float4*)(ap + i * 32 + 4) : z4;
    }
    bf16x8 bcur[6], bnxt[6];
    #pragma unroll
    for (int t = 0; t < 6; ++t) bcur[t] = *(const bf16x8*)(wp + (size_t)t * 16 * KP1);

    #pragma unroll
    for (int i = 0; i < 10; ++i) {
        if (i + 3 < 10) {
            int kb = (i + 3) * 32 + quad * 8;
            pa[(i + 3) & 3][0] = (kb + 4 <= DIN) ? *(const float4*)(ap + (i + 3) * 32) : z4;
            pa[(i + 3) & 3][1] = (kb + 8 <= DIN) ? *(const float4*)(ap + (i + 3) * 32 + 4) : z4;
        }
        if (i + 1 < 10) {
            #pragma unroll
            for (int t = 0; t < 6; ++t)
                bnxt[t] = *(const bf16x8*)(wp + (size_t)t * 16 * KP1 + (i + 1) * 32);
        }
        float4 a0 = pa[i & 3][0], a1 = pa[i & 3][1];
        bf16x8 af;
        af[0] = (short)f2bf(a0.x); af[1] = (short)f2bf(a0.y);
        af[2] = (short)f2bf(a0.z); af[3] = (short)f2bf(a0.w);
        af[4] = (short)f2bf(a1.x); af[5] = (short)f2bf(a1.y);
        af[6] = (short)f2bf(a1.z); af[7] = (short)f2bf(a1.w);
        #pragma unroll
        for (int t = 0; t < 6; ++t)
            acc[t] = __builtin_amdgcn_mfma_f32_16x16x32_bf16(af, bcur[t], acc[t], 0, 0, 0);
        #pragma unroll
        for (int t = 0; t < 6; ++t) bcur[t] = bnxt[t];
    }
    const int rbase = blockIdx.x * 64 + wv * 16 + quad * 4;
    #pragma unroll
    for (int r = 0; r < 4; ++r) {
        int rr = rbase + r;
        if (rr < NN) {
            float* cp = C + (size_t)rr * DH + m;
            #pragma unroll
            for (int t = 0; t < 6; ++t) cp[t * 16] = acc[t][r];
        }
    }
}

// ---------------- GEMM2: C[NN][96](f32) = a1b[NN][96](bf16) @ W2 ----------------
__global__ __launch_bounds__(256) void k_gemm2(const unsigned short* __restrict__ Ab,
        const unsigned short* __restrict__ WT, float* __restrict__ C) {
    const int tid = threadIdx.x;
    const int wv = tid >> 6;
    const int lane = tid & 63;
    const int m = lane & 15;
    const int quad = lane >> 4;
    const int row = blockIdx.x * 64 + wv * 16 + m;
    const int arow = row < NN ? row : NN - 1;
    const unsigned short* ap = Ab + (size_t)arow * DH + quad * 8;
    const unsigned short* wp = WT + (size_t)m * DH + quad * 8;
    bf16x8 af[3], bf[3][6];
    #pragma unroll
    for (int i = 0; i < 3; ++i) af[i] = *(const bf16x8*)(ap + i * 32);
    #pragma unroll
    for (int i = 0; i < 3; ++i)
        #pragma unroll
        for (int t = 0; t < 6; ++t)
            bf[i][t] = *(const bf16x8*)(wp + (size_t)t * 16 * DH + i * 32);
    f32x4 acc[6];
    #pragma unroll
    for (int t = 0; t < 6; ++t) acc[t] = (f32x4){0.f, 0.f, 0.f, 0.f};
    #pragma unroll
    for (int i = 0; i < 3; ++i)
        #pragma unroll
        for (int t = 0; t < 6; ++t)
            acc[t] = __builtin_amdgcn_mfma_f32_16x16x32_bf16(af[i], bf[i][t], acc[t], 0, 0, 0);
    const int rbase = blockIdx.x * 64 + wv * 16 + quad * 4;
    #pragma unroll
    for (int r = 0; r < 4; ++r) {
        int rr = rbase + r;
        if (rr < NN) {
            float* cp = C + (size_t)rr * DH + m;
            #pragma unroll
            for (int t = 0; t < 6; ++t) cp[t * 16] = acc[t][r];
        }
    }
}

// ---------------- aggregate + bias + relu (fp32 gather, 4-way MLP unroll) ----------------
#define QH (DH / 4)   // 24 float4 per node
template <bool BFOUT>
__global__ void k_agg(const float4* __restrict__ ht4, const float* __restrict__ dis,
                      const int* __restrict__ rowptr, const int* __restrict__ esrc,
                      const float4* __restrict__ bias4, float4* __restrict__ fout,
                      ushort4* __restrict__ bout) {
    int gid = blockIdx.x * blockDim.x + threadIdx.x;
    if (gid >= NN * QH) return;
    int n = gid / QH;
    int q = gid - n * QH;
    int beg = rowptr[n], end = rowptr[n + 1];
    float dn = dis[n];
    float4 h0 = ht4[(size_t)n * QH + q];
    float4 acc = make_float4(dn * h0.x, dn * h0.y, dn * h0.z, dn * h0.w);
    int e = beg;
    for (; e + 3 < end; e += 4) {
        int s0 = esrc[e], s1 = esrc[e + 1], s2 = esrc[e + 2], s3 = esrc[e + 3];
        float d0 = dis[s0], d1 = dis[s1], d2 = dis[s2], d3 = dis[s3];
        float4 v0 = ht4[(size_t)s0 * QH + q];
        float4 v1 = ht4[(size_t)s1 * QH + q];
        float4 v2 = ht4[(size_t)s2 * QH + q];
        float4 v3 = ht4[(size_t)s3 * QH + q];
        acc.x = fmaf(d0, v0.x, acc.x); acc.y = fmaf(d0, v0.y, acc.y);
        acc.z = fmaf(d0, v0.z, acc.z); acc.w = fmaf(d0, v0.w, acc.w);
        acc.x = fmaf(d1, v1.x, acc.x); acc.y = fmaf(d1, v1.y, acc.y);
        acc.z = fmaf(d1, v1.z, acc.z); acc.w = fmaf(d1, v1.w, acc.w);
        acc.x = fmaf(d2, v2.x, acc.x); acc.y = fmaf(d2, v2.y, acc.y);
        acc.z = fmaf(d2, v2.z, acc.z); acc.w = fmaf(d2, v2.w, acc.w);
        acc.x = fmaf(d3, v3.x, acc.x); acc.y = fmaf(d3, v3.y, acc.y);
        acc.z = fmaf(d3, v3.z, acc.z); acc.w = fmaf(d3, v3.w, acc.w);
    }
    for (; e < end; ++e) {
        int s = esrc[e];
        float ds = dis[s];
        float4 v = ht4[(size_t)s * QH + q];
        acc.x = fmaf(ds, v.x, acc.x);
        acc.y = fmaf(ds, v.y, acc.y);
        acc.z = fmaf(ds, v.z, acc.z);
        acc.w = fmaf(ds, v.w, acc.w);
    }
    float4 b = bias4[q];
    float4 r;
    r.x = fmaxf(fmaf(dn, acc.x, b.x), 0.f);
    r.y = fmaxf(fmaf(dn, acc.y, b.y), 0.f);
    r.z = fmaxf(fmaf(dn, acc.z, b.z), 0.f);
    r.w = fmaxf(fmaf(dn, acc.w, b.w), 0.f);
    if (BFOUT) {
        ushort4 o;
        o.x = f2bf(r.x); o.y = f2bf(r.y); o.z = f2bf(r.z); o.w = f2bf(r.w);
        bout[gid] = o;
    } else {
        fout[gid] = r;
    }
}

// ---------------- mean-pool: node-parallel partial sums ----------------
#define PNODES 128
__global__ void k_pool_partial(const float* __restrict__ h, const int* __restrict__ batch,
                               float* __restrict__ pooled, int* __restrict__ gcnt) {
    __shared__ int sbatch[PNODES];
    const int n0 = blockIdx.x * PNODES;
    const int nend = min(n0 + PNODES, NN);
    const int cnt = nend - n0;
    const int f = threadIdx.x;
    if (f < cnt) sbatch[f] = batch[n0 + f];
    __syncthreads();
    if (f < DH) {
        float acc = 0.f;
        int cur = sbatch[0];
        for (int i = 0; i < cnt; ++i) {
            int g = sbatch[i];
            if (g != cur) {
                atomicAdd(&pooled[cur * DH + f], acc);
                acc = 0.f; cur = g;
            }
            acc += h[(size_t)(n0 + i) * DH + f];
        }
        atomicAdd(&pooled[cur * DH + f], acc);
    } else if (f == DH) {
        int c = 0;
        int cur = sbatch[0];
        for (int i = 0; i < cnt; ++i) {
            int g = sbatch[i];
            if (g != cur) { atomicAdd(&gcnt[cur], c); c = 0; cur = g; }
            ++c;
        }
        atomicAdd(&gcnt[cur], c);
    }
}

__global__ void k_fc(const float* __restrict__ pooled, const int* __restrict__ gcnt,
                     const float* __restrict__ Wfc, const float* __restrict__ bfc,
                     float* __restrict__ out) {
    const int t = threadIdx.x;
    if (t >= NG * DOUTC) return;
    const int g = t / DOUTC;
    const int c = t - g * DOUTC;
    float inv = 1.f / fmaxf((float)gcnt[g], 1.f);
    float acc = bfc[c];
    #pragma unroll 8
    for (int j = 0; j < DH; ++j)
        acc += pooled[g * DH + j] * inv * Wfc[j * DOUTC + c];
    out[g * DOUTC + c] = acc;
}

extern "C" void kernel_launch(void* const* d_in, const int* in_sizes, int n_in,
                              void* d_out, int out_size, void* d_ws, size_t ws_size,
                              hipStream_t stream) {
    const float* x   = (const float*)d_in[0];
    const float* W1  = (const float*)d_in[1];
    const float* b1  = (const float*)d_in[2];
    const float* W2  = (const float*)d_in[3];
    const float* b2  = (const float*)d_in[4];
    const float* Wfc = (const float*)d_in[5];
    const float* bfc = (const float*)d_in[6];
    const int* src   = (const int*)d_in[7];
    const int* dst   = (const int*)d_in[8];
    const int* batch = (const int*)d_in[9];
    float* out = (float*)d_out;

    float* ht    = (float*)d_ws;              // NN*DH f32 (both GEMM outputs)
    float* hbuf  = ht + (size_t)NN * DH;      // NN*DH f32 (agg2 out)
    unsigned short* h1b = (unsigned short*)hbuf; // NN*DH bf16 (agg1 out, overlay)
    float* dis   = hbuf + (size_t)NN * DH;    // NN
    float* pooled= dis + NN;                  // NG*DH
    int* cnt     = (int*)(pooled + NG * DH);  // NN
    int* fill    = cnt + NN;                  // NN
    int* gcnt    = fill + NN;                 // NG
    int* rowptr  = gcnt + NG;                 // NN+1
    int* bsum    = rowptr + NN + 2;           // NSB
    int* esrc    = bsum + NSB;                // NE
    unsigned short* wt1 = (unsigned short*)(esrc + NE);  // DH*KP1
    unsigned short* wt2 = wt1 + DH * KP1;                // DH*DH

    const int TB = 256;
    k_init<<<(NN + TB - 1) / TB, TB, 0, stream>>>(cnt, fill, pooled, gcnt);
    k_hist<<<(NE + TB - 1) / TB, TB, 0, stream>>>(dst, cnt);
    k_scan1<<<NSB, SCB, 0, stream>>>(cnt, rowptr, bsum, dis);
    k_scan2<<<1, 256, 0, stream>>>(bsum, rowptr);
    k_scan3<<<NSB, SCB, 0, stream>>>(rowptr, bsum);
    k_scatter<<<(NE + TB - 1) / TB, TB, 0, stream>>>(src, dst, rowptr, fill, esrc);
    k_wt<<<(DH * KP1 + TB - 1) / TB, TB, 0, stream>>>(W1, wt1, DIN, KP1);
    k_wt<<<(DH * DH + TB - 1) / TB, TB, 0, stream>>>(W2, wt2, DH, DH);

    // layer 1
    k_gemm1<<<(NN + 63) / 64, 256, 0, stream>>>(x, wt1, ht);
    k_agg<true><<<(NN * QH + TB - 1) / TB, TB, 0, stream>>>(
        (const float4*)ht, dis, rowptr, esrc, (const float4*)b1,
        nullptr, (ushort4*)h1b);
    // layer 2
    k_gemm2<<<(NN + 63) / 64, 256, 0, stream>>>(h1b, wt2, ht);
    k_agg<false><<<(NN * QH + TB - 1) / TB, TB, 0, stream>>>(
        (const float4*)ht, dis, rowptr, esrc, (const float4*)b2,
        (float4*)hbuf, nullptr);
    // pool + fc
    k_pool_partial<<<(NN + PNODES - 1) / PNODES, 128, 0, stream>>>(hbuf, batch, pooled, gcnt);
    k_fc<<<1, 128, 0, stream>>>(pooled, gcnt, Wfc, bfc, out);
}

// Round 10
// 361.061 us; speedup vs baseline: 2.3498x; 1.0235x over previous
//
#include <hip/hip_runtime.h>
#include <hip/hip_bf16.h>

#define NN 50000
#define NE 800000
#define DIN 300
#define KP1 320
#define DH 96
#define DOUTC 2
#define NG 64

#define SCB 256
#define NSB ((NN + SCB - 1) / SCB)   // 196 scan blocks

#define NKB 10                        // gemm1 k-blocks (320/32)
#define NFRAG (NKB * 6 * 64)          // 3840 B-fragments of 16 B

typedef __attribute__((ext_vector_type(8))) short bf16x8;
typedef __attribute__((ext_vector_type(4))) float f32x4;

__device__ inline unsigned short f2bf(float f) {
    unsigned int u = __float_as_uint(f);
    unsigned int r = (u + 0x7fffu + ((u >> 16) & 1u)) >> 16;
    return (unsigned short)r;
}

// ---------------- CSR build ----------------
__global__ void k_init(int* cnt, int* fill, float* pooled, int* gcnt) {
    int i = blockIdx.x * blockDim.x + threadIdx.x;
    if (i < NN) { cnt[i] = 0; fill[i] = 0; }
    if (i < NG * DH) pooled[i] = 0.f;
    if (i < NG) gcnt[i] = 0;
}

__global__ void k_hist(const int* __restrict__ dst, int* cnt) {
    int e = blockIdx.x * blockDim.x + threadIdx.x;
    if (e < NE) atomicAdd(&cnt[dst[e]], 1);
}

__global__ void k_scan1(const int* __restrict__ cnt, int* __restrict__ rowptr,
                        int* __restrict__ bsum, float* __restrict__ dis) {
    __shared__ int s[SCB];
    const int t = threadIdx.x;
    const int i = blockIdx.x * SCB + t;
    int v = (i < NN) ? cnt[i] : 0;
    if (i < NN) dis[i] = rsqrtf(1.0f + (float)v);
    s[t] = v;
    __syncthreads();
    #pragma unroll
    for (int off = 1; off < SCB; off <<= 1) {
        int u = (t >= off) ? s[t - off] : 0;
        __syncthreads();
        s[t] += u;
        __syncthreads();
    }
    if (i < NN) rowptr[i] = s[t] - v;
    if (t == SCB - 1) bsum[blockIdx.x] = s[t];
}

__global__ void k_scan2(int* __restrict__ bsum, int* __restrict__ rowptr) {
    __shared__ int s[256];
    const int t = threadIdx.x;
    int v = (t < NSB) ? bsum[t] : 0;
    s[t] = v;
    __syncthreads();
    #pragma unroll
    for (int off = 1; off < 256; off <<= 1) {
        int u = (t >= off) ? s[t - off] : 0;
        __syncthreads();
        s[t] += u;
        __syncthreads();
    }
    if (t < NSB) bsum[t] = s[t] - v;
    if (t == 255) rowptr[NN] = s[t];
}

__global__ void k_scan3(int* __restrict__ rowptr, const int* __restrict__ bsum) {
    int i = blockIdx.x * SCB + threadIdx.x;
    if (i < NN) rowptr[i] += bsum[blockIdx.x];
}

__global__ void k_scatter(const int* __restrict__ src, const int* __restrict__ dst,
                          const int* __restrict__ rowptr, int* fill, int* esrc) {
    int e = blockIdx.x * blockDim.x + threadIdx.x;
    if (e < NE) {
        int d = dst[e];
        int pos = rowptr[d] + atomicAdd(&fill[d], 1);
        esrc[pos] = src[e];
    }
}

// ---------------- W2 -> W^T bf16 (row-major, gemm2) ----------------
__global__ void k_wt(const float* __restrict__ W, unsigned short* __restrict__ WT,
                     int K, int KPAD) {
    int i = blockIdx.x * blockDim.x + threadIdx.x;
    if (i >= DH * KPAD) return;
    int j = i / KPAD, k = i - j * KPAD;
    WT[i] = (k < K) ? f2bf(W[(size_t)k * DH + j]) : (unsigned short)0;
}

// ---------------- W1 -> fragment-major bf16 for gemm1 LDS staging ----------------
// layout: frag f = (i*6 + t)*64 + lane; element j in [0,8)
// value = W1[col = i*32 + (lane>>4)*8 + j][row = (lane&15) + 16*t], 0 if col>=DIN
__global__ void k_wt1f(const float* __restrict__ W, unsigned short* __restrict__ WF) {
    int g = blockIdx.x * blockDim.x + threadIdx.x;   // over NFRAG*8
    if (g >= NFRAG * 8) return;
    int j = g & 7;
    int f = g >> 3;
    int lane = f & 63;
    int ft = f >> 6;        // i*6 + t
    int t = ft % 6;
    int i = ft / 6;
    int row = (lane & 15) + 16 * t;
    int col = i * 32 + (lane >> 4) * 8 + j;
    WF[g] = (col < DIN) ? f2bf(W[(size_t)col * DH + row]) : (unsigned short)0;
}

// ---------------- GEMM1: C[NN][96](f32) = x[NN][300] @ W1 ----------------
// B entirely in LDS (fragment-major, conflict-free ds_read_b128, lgkmcnt);
// A is the ONLY vmem stream -> depth-4 ring / distance-3 prefetch gets a true
// 3-iteration latency budget (R9's mixed A/B vmcnt queue collapsed it to ~1).
__global__ __launch_bounds__(256) void k_gemm1(const float* __restrict__ A,
        const unsigned short* __restrict__ WF, float* __restrict__ C) {
    __shared__ unsigned short ldsB[NFRAG * 8];   // 61440 B
    const int tid = threadIdx.x;
    // stage B: coalesced 16B copies
    {
        const uint4* srcv = (const uint4*)WF;
        uint4* dstv = (uint4*)ldsB;
        #pragma unroll
        for (int f = 0; f < NFRAG / 256; ++f)
            dstv[f * 256 + tid] = srcv[f * 256 + tid];
    }
    __syncthreads();

    const int wv = tid >> 6;
    const int lane = tid & 63;
    const int m = lane & 15;
    const int quad = lane >> 4;
    const int row = blockIdx.x * 64 + wv * 16 + m;
    const int arow = row < NN ? row : NN - 1;
    const float* ap = A + (size_t)arow * DIN + quad * 8;
    const float4 z4 = make_float4(0.f, 0.f, 0.f, 0.f);
    const bf16x8* lb = (const bf16x8*)ldsB;
    f32x4 acc[6];
    #pragma unroll
    for (int t = 0; t < 6; ++t) acc[t] = (f32x4){0.f, 0.f, 0.f, 0.f};

    float4 pa[4][2];
    #pragma unroll
    for (int i = 0; i < 3; ++i) {
        int kb = i * 32 + quad * 8;
        pa[i][0] = (kb + 4 <= DIN) ? *(const float4*)(ap + i * 32) : z4;
        pa[i][1] = (kb + 8 <= DIN) ? *(const float4*)(ap + i * 32 + 4) : z4;
    }

    #pragma unroll
    for (int i = 0; i < NKB; ++i) {
        if (i + 3 < NKB) {
            int kb = (i + 3) * 32 + quad * 8;
            pa[(i + 3) & 3][0] = (kb + 4 <= DIN) ? *(const float4*)(ap + (i + 3) * 32) : z4;
            pa[(i + 3) & 3][1] = (kb + 8 <= DIN) ? *(const float4*)(ap + (i + 3) * 32 + 4) : z4;
        }
        float4 a0 = pa[i & 3][0], a1 = pa[i & 3][1];
        bf16x8 af;
        af[0] = (short)f2bf(a0.x); af[1] = (short)f2bf(a0.y);
        af[2] = (short)f2bf(a0.z); af[3] = (short)f2bf(a0.w);
        af[4] = (short)f2bf(a1.x); af[5] = (short)f2bf(a1.y);
        af[6] = (short)f2bf(a1.z); af[7] = (short)f2bf(a1.w);
        #pragma unroll
        for (int t = 0; t < 6; ++t) {
            bf16x8 bf = lb[(i * 6 + t) * 64 + lane];
            acc[t] = __builtin_amdgcn_mfma_f32_16x16x32_bf16(af, bf, acc[t], 0, 0, 0);
        }
    }
    const int rbase = blockIdx.x * 64 + wv * 16 + quad * 4;
    #pragma unroll
    for (int r = 0; r < 4; ++r) {
        int rr = rbase + r;
        if (rr < NN) {
            float* cp = C + (size_t)rr * DH + m;
            #pragma unroll
            for (int t = 0; t < 6; ++t) cp[t * 16] = acc[t][r];
        }
    }
}

// ---------------- GEMM2: C[NN][96](f32) = a1b[NN][96](bf16) @ W2 ----------------
__global__ __launch_bounds__(256) void k_gemm2(const unsigned short* __restrict__ Ab,
        const unsigned short* __restrict__ WT, float* __restrict__ C) {
    const int tid = threadIdx.x;
    const int wv = tid >> 6;
    const int lane = tid & 63;
    const int m = lane & 15;
    const int quad = lane >> 4;
    const int row = blockIdx.x * 64 + wv * 16 + m;
    const int arow = row < NN ? row : NN - 1;
    const unsigned short* ap = Ab + (size_t)arow * DH + quad * 8;
    const unsigned short* wp = WT + (size_t)m * DH + quad * 8;
    bf16x8 af[3], bf[3][6];
    #pragma unroll
    for (int i = 0; i < 3; ++i) af[i] = *(const bf16x8*)(ap + i * 32);
    #pragma unroll
    for (int i = 0; i < 3; ++i)
        #pragma unroll
        for (int t = 0; t < 6; ++t)
            bf[i][t] = *(const bf16x8*)(wp + (size_t)t * 16 * DH + i * 32);
    f32x4 acc[6];
    #pragma unroll
    for (int t = 0; t < 6; ++t) acc[t] = (f32x4){0.f, 0.f, 0.f, 0.f};
    #pragma unroll
    for (int i = 0; i < 3; ++i)
        #pragma unroll
        for (int t = 0; t < 6; ++t)
            acc[t] = __builtin_amdgcn_mfma_f32_16x16x32_bf16(af[i], bf[i][t], acc[t], 0, 0, 0);
    const int rbase = blockIdx.x * 64 + wv * 16 + quad * 4;
    #pragma unroll
    for (int r = 0; r < 4; ++r) {
        int rr = rbase + r;
        if (rr < NN) {
            float* cp = C + (size_t)rr * DH + m;
            #pragma unroll
            for (int t = 0; t < 6; ++t) cp[t * 16] = acc[t][r];
        }
    }
}

// ---------------- aggregate + bias + relu (fp32 gather, 4-way MLP unroll) ----------------
#define QH (DH / 4)   // 24 float4 per node
template <bool BFOUT>
__global__ void k_agg(const float4* __restrict__ ht4, const float* __restrict__ dis,
                      const int* __restrict__ rowptr, const int* __restrict__ esrc,
                      const float4* __restrict__ bias4, float4* __restrict__ fout,
                      ushort4* __restrict__ bout) {
    int gid = blockIdx.x * blockDim.x + threadIdx.x;
    if (gid >= NN * QH) return;
    int n = gid / QH;
    int q = gid - n * QH;
    int beg = rowptr[n], end = rowptr[n + 1];
    float dn = dis[n];
    float4 h0 = ht4[(size_t)n * QH + q];
    float4 acc = make_float4(dn * h0.x, dn * h0.y, dn * h0.z, dn * h0.w);
    int e = beg;
    for (; e + 3 < end; e += 4) {
        int s0 = esrc[e], s1 = esrc[e + 1], s2 = esrc[e + 2], s3 = esrc[e + 3];
        float d0 = dis[s0], d1 = dis[s1], d2 = dis[s2], d3 = dis[s3];
        float4 v0 = ht4[(size_t)s0 * QH + q];
        float4 v1 = ht4[(size_t)s1 * QH + q];
        float4 v2 = ht4[(size_t)s2 * QH + q];
        float4 v3 = ht4[(size_t)s3 * QH + q];
        acc.x = fmaf(d0, v0.x, acc.x); acc.y = fmaf(d0, v0.y, acc.y);
        acc.z = fmaf(d0, v0.z, acc.z); acc.w = fmaf(d0, v0.w, acc.w);
        acc.x = fmaf(d1, v1.x, acc.x); acc.y = fmaf(d1, v1.y, acc.y);
        acc.z = fmaf(d1, v1.z, acc.z); acc.w = fmaf(d1, v1.w, acc.w);
        acc.x = fmaf(d2, v2.x, acc.x); acc.y = fmaf(d2, v2.y, acc.y);
        acc.z = fmaf(d2, v2.z, acc.z); acc.w = fmaf(d2, v2.w, acc.w);
        acc.x = fmaf(d3, v3.x, acc.x); acc.y = fmaf(d3, v3.y, acc.y);
        acc.z = fmaf(d3, v3.z, acc.z); acc.w = fmaf(d3, v3.w, acc.w);
    }
    for (; e < end; ++e) {
        int s = esrc[e];
        float ds = dis[s];
        float4 v = ht4[(size_t)s * QH + q];
        acc.x = fmaf(ds, v.x, acc.x);
        acc.y = fmaf(ds, v.y, acc.y);
        acc.z = fmaf(ds, v.z, acc.z);
        acc.w = fmaf(ds, v.w, acc.w);
    }
    float4 b = bias4[q];
    float4 r;
    r.x = fmaxf(fmaf(dn, acc.x, b.x), 0.f);
    r.y = fmaxf(fmaf(dn, acc.y, b.y), 0.f);
    r.z = fmaxf(fmaf(dn, acc.z, b.z), 0.f);
    r.w = fmaxf(fmaf(dn, acc.w, b.w), 0.f);
    if (BFOUT) {
        ushort4 o;
        o.x = f2bf(r.x); o.y = f2bf(r.y); o.z = f2bf(r.z); o.w = f2bf(r.w);
        bout[gid] = o;
    } else {
        fout[gid] = r;
    }
}

// ---------------- mean-pool: node-parallel partial sums ----------------
#define PNODES 128
__global__ void k_pool_partial(const float* __restrict__ h, const int* __restrict__ batch,
                               float* __restrict__ pooled, int* __restrict__ gcnt) {
    __shared__ int sbatch[PNODES];
    const int n0 = blockIdx.x * PNODES;
    const int nend = min(n0 + PNODES, NN);
    const int cnt = nend - n0;
    const int f = threadIdx.x;
    if (f < cnt) sbatch[f] = batch[n0 + f];
    __syncthreads();
    if (f < DH) {
        float acc = 0.f;
        int cur = sbatch[0];
        for (int i = 0; i < cnt; ++i) {
            int g = sbatch[i];
            if (g != cur) {
                atomicAdd(&pooled[cur * DH + f], acc);
                acc = 0.f; cur = g;
            }
            acc += h[(size_t)(n0 + i) * DH + f];
        }
        atomicAdd(&pooled[cur * DH + f], acc);
    } else if (f == DH) {
        int c = 0;
        int cur = sbatch[0];
        for (int i = 0; i < cnt; ++i) {
            int g = sbatch[i];
            if (g != cur) { atomicAdd(&gcnt[cur], c); c = 0; cur = g; }
            ++c;
        }
        atomicAdd(&gcnt[cur], c);
    }
}

__global__ void k_fc(const float* __restrict__ pooled, const int* __restrict__ gcnt,
                     const float* __restrict__ Wfc, const float* __restrict__ bfc,
                     float* __restrict__ out) {
    const int t = threadIdx.x;
    if (t >= NG * DOUTC) return;
    const int g = t / DOUTC;
    const int c = t - g * DOUTC;
    float inv = 1.f / fmaxf((float)gcnt[g], 1.f);
    float acc = bfc[c];
    #pragma unroll 8
    for (int j = 0; j < DH; ++j)
        acc += pooled[g * DH + j] * inv * Wfc[j * DOUTC + c];
    out[g * DOUTC + c] = acc;
}

extern "C" void kernel_launch(void* const* d_in, const int* in_sizes, int n_in,
                              void* d_out, int out_size, void* d_ws, size_t ws_size,
                              hipStream_t stream) {
    const float* x   = (const float*)d_in[0];
    const float* W1  = (const float*)d_in[1];
    const float* b1  = (const float*)d_in[2];
    const float* W2  = (const float*)d_in[3];
    const float* b2  = (const float*)d_in[4];
    const float* Wfc = (const float*)d_in[5];
    const float* bfc = (const float*)d_in[6];
    const int* src   = (const int*)d_in[7];
    const int* dst   = (const int*)d_in[8];
    const int* batch = (const int*)d_in[9];
    float* out = (float*)d_out;

    float* ht    = (float*)d_ws;              // NN*DH f32 (both GEMM outputs)
    float* hbuf  = ht + (size_t)NN * DH;      // NN*DH f32 (agg2 out)
    unsigned short* h1b = (unsigned short*)hbuf; // NN*DH bf16 (agg1 out, overlay)
    float* dis   = hbuf + (size_t)NN * DH;    // NN
    float* pooled= dis + NN;                  // NG*DH
    int* cnt     = (int*)(pooled + NG * DH);  // NN
    int* fill    = cnt + NN;                  // NN
    int* gcnt    = fill + NN;                 // NG
    int* rowptr  = gcnt + NG;                 // NN+1
    int* bsum    = rowptr + NN + 2;           // NSB
    int* esrc    = bsum + NSB;                // NE
    unsigned short* wt1f = (unsigned short*)(esrc + NE); // NFRAG*8 = DH*KP1
    unsigned short* wt2  = wt1f + NFRAG * 8;             // DH*DH

    const int TB = 256;
    k_init<<<(NN + TB - 1) / TB, TB, 0, stream>>>(cnt, fill, pooled, gcnt);
    k_hist<<<(NE + TB - 1) / TB, TB, 0, stream>>>(dst, cnt);
    k_scan1<<<NSB, SCB, 0, stream>>>(cnt, rowptr, bsum, dis);
    k_scan2<<<1, 256, 0, stream>>>(bsum, rowptr);
    k_scan3<<<NSB, SCB, 0, stream>>>(rowptr, bsum);
    k_scatter<<<(NE + TB - 1) / TB, TB, 0, stream>>>(src, dst, rowptr, fill, esrc);
    k_wt1f<<<(NFRAG * 8 + TB - 1) / TB, TB, 0, stream>>>(W1, wt1f);
    k_wt<<<(DH * DH + TB - 1) / TB, TB, 0, stream>>>(W2, wt2, DH, DH);

    // layer 1
    k_gemm1<<<(NN + 63) / 64, 256, 0, stream>>>(x, wt1f, ht);
    k_agg<true><<<(NN * QH + TB - 1) / TB, TB, 0, stream>>>(
        (const float4*)ht, dis, rowptr, esrc, (const float4*)b1,
        nullptr, (ushort4*)h1b);
    // layer 2
    k_gemm2<<<(NN + 63) / 64, 256, 0, stream>>>(h1b, wt2, ht);
    k_agg<false><<<(NN * QH + TB - 1) / TB, TB, 0, stream>>>(
        (const float4*)ht, dis, rowptr, esrc, (const float4*)b2,
        (float4*)hbuf, nullptr);
    // pool + fc
    k_pool_partial<<<(NN + PNODES - 1) / PNODES, 128, 0, stream>>>(hbuf, batch, pooled, gcnt);
    k_fc<<<1, 128, 0, stream>>>(pooled, gcnt, Wfc, bfc, out);
}

// Round 11
// 346.239 us; speedup vs baseline: 2.4504x; 1.0428x over previous
//
#include <hip/hip_runtime.h>
#include <hip/hip_bf16.h>

#define NN 50000
#define NE 800000
#define DIN 300
#define KP1 320
#define DH 96
#define DOUTC 2
#define NG 64

#define SCB 256
#define NSB ((NN + SCB - 1) / SCB)   // 196 scan blocks

#define NKB 10                        // gemm1 k-blocks (320/32)
#define NFRAG (NKB * 6 * 64)          // 3840 B-fragments of 16 B

typedef __attribute__((ext_vector_type(8))) short bf16x8;
typedef __attribute__((ext_vector_type(4))) float f32x4;

__device__ inline unsigned short f2bf(float f) {
    unsigned int u = __float_as_uint(f);
    unsigned int r = (u + 0x7fffu + ((u >> 16) & 1u)) >> 16;
    return (unsigned short)r;
}

// ---------------- CSR build ----------------
__global__ void k_init(int* cnt, int* fill, float* pooled, int* gcnt) {
    int i = blockIdx.x * blockDim.x + threadIdx.x;
    if (i < NN) { cnt[i] = 0; fill[i] = 0; }
    if (i < NG * DH) pooled[i] = 0.f;
    if (i < NG) gcnt[i] = 0;
}

__global__ void k_hist(const int* __restrict__ dst, int* cnt) {
    int e = blockIdx.x * blockDim.x + threadIdx.x;
    if (e < NE) atomicAdd(&cnt[dst[e]], 1);
}

__global__ void k_scan1(const int* __restrict__ cnt, int* __restrict__ rowptr,
                        int* __restrict__ bsum, float* __restrict__ dis) {
    __shared__ int s[SCB];
    const int t = threadIdx.x;
    const int i = blockIdx.x * SCB + t;
    int v = (i < NN) ? cnt[i] : 0;
    if (i < NN) dis[i] = rsqrtf(1.0f + (float)v);
    s[t] = v;
    __syncthreads();
    #pragma unroll
    for (int off = 1; off < SCB; off <<= 1) {
        int u = (t >= off) ? s[t - off] : 0;
        __syncthreads();
        s[t] += u;
        __syncthreads();
    }
    if (i < NN) rowptr[i] = s[t] - v;
    if (t == SCB - 1) bsum[blockIdx.x] = s[t];
}

__global__ void k_scan2(int* __restrict__ bsum, int* __restrict__ rowptr) {
    __shared__ int s[256];
    const int t = threadIdx.x;
    int v = (t < NSB) ? bsum[t] : 0;
    s[t] = v;
    __syncthreads();
    #pragma unroll
    for (int off = 1; off < 256; off <<= 1) {
        int u = (t >= off) ? s[t - off] : 0;
        __syncthreads();
        s[t] += u;
        __syncthreads();
    }
    if (t < NSB) bsum[t] = s[t] - v;
    if (t == 255) rowptr[NN] = s[t];
}

__global__ void k_scan3(int* __restrict__ rowptr, const int* __restrict__ bsum) {
    int i = blockIdx.x * SCB + threadIdx.x;
    if (i < NN) rowptr[i] += bsum[blockIdx.x];
}

__global__ void k_scatter(const int* __restrict__ src, const int* __restrict__ dst,
                          const int* __restrict__ rowptr, int* fill, int* esrc) {
    int e = blockIdx.x * blockDim.x + threadIdx.x;
    if (e < NE) {
        int d = dst[e];
        int pos = rowptr[d] + atomicAdd(&fill[d], 1);
        __builtin_nontemporal_store(src[e], &esrc[pos]);
    }
}

// ---------------- W2 -> W^T bf16 (row-major, gemm2) ----------------
__global__ void k_wt(const float* __restrict__ W, unsigned short* __restrict__ WT,
                     int K, int KPAD) {
    int i = blockIdx.x * blockDim.x + threadIdx.x;
    if (i >= DH * KPAD) return;
    int j = i / KPAD, k = i - j * KPAD;
    WT[i] = (k < K) ? f2bf(W[(size_t)k * DH + j]) : (unsigned short)0;
}

// ---------------- W1 -> fragment-major bf16 for gemm1 LDS staging ----------------
__global__ void k_wt1f(const float* __restrict__ W, unsigned short* __restrict__ WF) {
    int g = blockIdx.x * blockDim.x + threadIdx.x;   // over NFRAG*8
    if (g >= NFRAG * 8) return;
    int j = g & 7;
    int f = g >> 3;
    int lane = f & 63;
    int ft = f >> 6;        // i*6 + t
    int t = ft % 6;
    int i = ft / 6;
    int row = (lane & 15) + 16 * t;
    int col = i * 32 + (lane >> 4) * 8 + j;
    WF[g] = (col < DIN) ? f2bf(W[(size_t)col * DH + row]) : (unsigned short)0;
}

// ---------------- GEMM1: C[NN][96](f32) = x[NN][300] @ W1 ----------------
__global__ __launch_bounds__(256) void k_gemm1(const float* __restrict__ A,
        const unsigned short* __restrict__ WF, float* __restrict__ C) {
    __shared__ unsigned short ldsB[NFRAG * 8];   // 61440 B
    const int tid = threadIdx.x;
    {
        const uint4* srcv = (const uint4*)WF;
        uint4* dstv = (uint4*)ldsB;
        #pragma unroll
        for (int f = 0; f < NFRAG / 256; ++f)
            dstv[f * 256 + tid] = srcv[f * 256 + tid];
    }
    __syncthreads();

    const int wv = tid >> 6;
    const int lane = tid & 63;
    const int m = lane & 15;
    const int quad = lane >> 4;
    const int row = blockIdx.x * 64 + wv * 16 + m;
    const int arow = row < NN ? row : NN - 1;
    const float* ap = A + (size_t)arow * DIN + quad * 8;
    const float4 z4 = make_float4(0.f, 0.f, 0.f, 0.f);
    const bf16x8* lb = (const bf16x8*)ldsB;
    f32x4 acc[6];
    #pragma unroll
    for (int t = 0; t < 6; ++t) acc[t] = (f32x4){0.f, 0.f, 0.f, 0.f};

    float4 pa[4][2];
    #pragma unroll
    for (int i = 0; i < 3; ++i) {
        int kb = i * 32 + quad * 8;
        pa[i][0] = (kb + 4 <= DIN) ? *(const float4*)(ap + i * 32) : z4;
        pa[i][1] = (kb + 8 <= DIN) ? *(const float4*)(ap + i * 32 + 4) : z4;
    }

    #pragma unroll
    for (int i = 0; i < NKB; ++i) {
        if (i + 3 < NKB) {
            int kb = (i + 3) * 32 + quad * 8;
            pa[(i + 3) & 3][0] = (kb + 4 <= DIN) ? *(const float4*)(ap + (i + 3) * 32) : z4;
            pa[(i + 3) & 3][1] = (kb + 8 <= DIN) ? *(const float4*)(ap + (i + 3) * 32 + 4) : z4;
        }
        float4 a0 = pa[i & 3][0], a1 = pa[i & 3][1];
        bf16x8 af;
        af[0] = (short)f2bf(a0.x); af[1] = (short)f2bf(a0.y);
        af[2] = (short)f2bf(a0.z); af[3] = (short)f2bf(a0.w);
        af[4] = (short)f2bf(a1.x); af[5] = (short)f2bf(a1.y);
        af[6] = (short)f2bf(a1.z); af[7] = (short)f2bf(a1.w);
        #pragma unroll
        for (int t = 0; t < 6; ++t) {
            bf16x8 bf = lb[(i * 6 + t) * 64 + lane];
            acc[t] = __builtin_amdgcn_mfma_f32_16x16x32_bf16(af, bf, acc[t], 0, 0, 0);
        }
    }
    const int rbase = blockIdx.x * 64 + wv * 16 + quad * 4;
    #pragma unroll
    for (int r = 0; r < 4; ++r) {
        int rr = rbase + r;
        if (rr < NN) {
            float* cp = C + (size_t)rr * DH + m;
            #pragma unroll
            for (int t = 0; t < 6; ++t) cp[t * 16] = acc[t][r];
        }
    }
}

// ---------------- GEMM2: C[NN][96](f32) = a1b[NN][96](bf16) @ W2 ----------------
__global__ __launch_bounds__(256) void k_gemm2(const unsigned short* __restrict__ Ab,
        const unsigned short* __restrict__ WT, float* __restrict__ C) {
    const int tid = threadIdx.x;
    const int wv = tid >> 6;
    const int lane = tid & 63;
    const int m = lane & 15;
    const int quad = lane >> 4;
    const int row = blockIdx.x * 64 + wv * 16 + m;
    const int arow = row < NN ? row : NN - 1;
    const unsigned short* ap = Ab + (size_t)arow * DH + quad * 8;
    const unsigned short* wp = WT + (size_t)m * DH + quad * 8;
    bf16x8 af[3], bf[3][6];
    #pragma unroll
    for (int i = 0; i < 3; ++i) af[i] = *(const bf16x8*)(ap + i * 32);
    #pragma unroll
    for (int i = 0; i < 3; ++i)
        #pragma unroll
        for (int t = 0; t < 6; ++t)
            bf[i][t] = *(const bf16x8*)(wp + (size_t)t * 16 * DH + i * 32);
    f32x4 acc[6];
    #pragma unroll
    for (int t = 0; t < 6; ++t) acc[t] = (f32x4){0.f, 0.f, 0.f, 0.f};
    #pragma unroll
    for (int i = 0; i < 3; ++i)
        #pragma unroll
        for (int t = 0; t < 6; ++t)
            acc[t] = __builtin_amdgcn_mfma_f32_16x16x32_bf16(af[i], bf[i][t], acc[t], 0, 0, 0);
    const int rbase = blockIdx.x * 64 + wv * 16 + quad * 4;
    #pragma unroll
    for (int r = 0; r < 4; ++r) {
        int rr = rbase + r;
        if (rr < NN) {
            float* cp = C + (size_t)rr * DH + m;
            #pragma unroll
            for (int t = 0; t < 6; ++t) cp[t * 16] = acc[t][r];
        }
    }
}

// ---------------- aggregate + bias + relu (fp32 gather, 4-way MLP unroll) ----------------
#define QH (DH / 4)   // 24 float4 per node
template <bool BFOUT>
__global__ void k_agg(const float4* __restrict__ ht4, const float* __restrict__ dis,
                      const int* __restrict__ rowptr, const int* __restrict__ esrc,
                      const float4* __restrict__ bias4, float4* __restrict__ fout,
                      ushort4* __restrict__ bout) {
    int gid = blockIdx.x * blockDim.x + threadIdx.x;
    if (gid >= NN * QH) return;
    int n = gid / QH;
    int q = gid - n * QH;
    int beg = rowptr[n], end = rowptr[n + 1];
    float dn = dis[n];
    float4 h0 = ht4[(size_t)n * QH + q];
    float4 acc = make_float4(dn * h0.x, dn * h0.y, dn * h0.z, dn * h0.w);
    int e = beg;
    for (; e + 3 < end; e += 4) {
        int s0 = esrc[e], s1 = esrc[e + 1], s2 = esrc[e + 2], s3 = esrc[e + 3];
        float d0 = dis[s0], d1 = dis[s1], d2 = dis[s2], d3 = dis[s3];
        float4 v0 = ht4[(size_t)s0 * QH + q];
        float4 v1 = ht4[(size_t)s1 * QH + q];
        float4 v2 = ht4[(size_t)s2 * QH + q];
        float4 v3 = ht4[(size_t)s3 * QH + q];
        acc.x = fmaf(d0, v0.x, acc.x); acc.y = fmaf(d0, v0.y, acc.y);
        acc.z = fmaf(d0, v0.z, acc.z); acc.w = fmaf(d0, v0.w, acc.w);
        acc.x = fmaf(d1, v1.x, acc.x); acc.y = fmaf(d1, v1.y, acc.y);
        acc.z = fmaf(d1, v1.z, acc.z); acc.w = fmaf(d1, v1.w, acc.w);
        acc.x = fmaf(d2, v2.x, acc.x); acc.y = fmaf(d2, v2.y, acc.y);
        acc.z = fmaf(d2, v2.z, acc.z); acc.w = fmaf(d2, v2.w, acc.w);
        acc.x = fmaf(d3, v3.x, acc.x); acc.y = fmaf(d3, v3.y, acc.y);
        acc.z = fmaf(d3, v3.z, acc.z); acc.w = fmaf(d3, v3.w, acc.w);
    }
    for (; e < end; ++e) {
        int s = esrc[e];
        float ds = dis[s];
        float4 v = ht4[(size_t)s * QH + q];
        acc.x = fmaf(ds, v.x, acc.x);
        acc.y = fmaf(ds, v.y, acc.y);
        acc.z = fmaf(ds, v.z, acc.z);
        acc.w = fmaf(ds, v.w, acc.w);
    }
    float4 b = bias4[q];
    float4 r;
    r.x = fmaxf(fmaf(dn, acc.x, b.x), 0.f);
    r.y = fmaxf(fmaf(dn, acc.y, b.y), 0.f);
    r.z = fmaxf(fmaf(dn, acc.z, b.z), 0.f);
    r.w = fmaxf(fmaf(dn, acc.w, b.w), 0.f);
    if (BFOUT) {
        ushort4 o;
        o.x = f2bf(r.x); o.y = f2bf(r.y); o.z = f2bf(r.z); o.w = f2bf(r.w);
        bout[gid] = o;
    } else {
        fout[gid] = r;
    }
}

// ---------------- mean-pool: node-parallel partial sums ----------------
// PNODES=32: 1563 blocks x 2 waves ~= 12 waves/CU (R10's 128-node chunks gave
// only ~3 waves/CU -> 47 us latency-bound at 207 GB/s).
#define PNODES 32
__global__ void k_pool_partial(const float* __restrict__ h, const int* __restrict__ batch,
                               float* __restrict__ pooled, int* __restrict__ gcnt) {
    __shared__ int sbatch[PNODES];
    const int n0 = blockIdx.x * PNODES;
    const int nend = min(n0 + PNODES, NN);
    const int cnt = nend - n0;
    const int f = threadIdx.x;   // 128 threads
    if (f < cnt) sbatch[f] = batch[n0 + f];
    __syncthreads();
    if (f < DH) {
        float acc = 0.f;
        int cur = sbatch[0];
        for (int i = 0; i < cnt; ++i) {
            int g = sbatch[i];
            if (g != cur) {
                atomicAdd(&pooled[cur * DH + f], acc);
                acc = 0.f; cur = g;
            }
            acc += h[(size_t)(n0 + i) * DH + f];
        }
        atomicAdd(&pooled[cur * DH + f], acc);
    } else if (f == DH) {
        int c = 0;
        int cur = sbatch[0];
        for (int i = 0; i < cnt; ++i) {
            int g = sbatch[i];
            if (g != cur) { atomicAdd(&gcnt[cur], c); c = 0; cur = g; }
            ++c;
        }
        atomicAdd(&gcnt[cur], c);
    }
}

__global__ void k_fc(const float* __restrict__ pooled, const int* __restrict__ gcnt,
                     const float* __restrict__ Wfc, const float* __restrict__ bfc,
                     float* __restrict__ out) {
    const int t = threadIdx.x;
    if (t >= NG * DOUTC) return;
    const int g = t / DOUTC;
    const int c = t - g * DOUTC;
    float inv = 1.f / fmaxf((float)gcnt[g], 1.f);
    float acc = bfc[c];
    #pragma unroll 8
    for (int j = 0; j < DH; ++j)
        acc += pooled[g * DH + j] * inv * Wfc[j * DOUTC + c];
    out[g * DOUTC + c] = acc;
}

extern "C" void kernel_launch(void* const* d_in, const int* in_sizes, int n_in,
                              void* d_out, int out_size, void* d_ws, size_t ws_size,
                              hipStream_t stream) {
    const float* x   = (const float*)d_in[0];
    const float* W1  = (const float*)d_in[1];
    const float* b1  = (const float*)d_in[2];
    const float* W2  = (const float*)d_in[3];
    const float* b2  = (const float*)d_in[4];
    const float* Wfc = (const float*)d_in[5];
    const float* bfc = (const float*)d_in[6];
    const int* src   = (const int*)d_in[7];
    const int* dst   = (const int*)d_in[8];
    const int* batch = (const int*)d_in[9];
    float* out = (float*)d_out;

    float* ht    = (float*)d_ws;              // NN*DH f32 (both GEMM outputs)
    float* hbuf  = ht + (size_t)NN * DH;      // NN*DH f32 (agg2 out)
    unsigned short* h1b = (unsigned short*)hbuf; // NN*DH bf16 (agg1 out, overlay)
    float* dis   = hbuf + (size_t)NN * DH;    // NN
    float* pooled= dis + NN;                  // NG*DH
    int* cnt     = (int*)(pooled + NG * DH);  // NN
    int* fill    = cnt + NN;                  // NN
    int* gcnt    = fill + NN;                 // NG
    int* rowptr  = gcnt + NG;                 // NN+1
    int* bsum    = rowptr + NN + 2;           // NSB
    int* esrc    = bsum + NSB;                // NE
    unsigned short* wt1f = (unsigned short*)(esrc + NE); // NFRAG*8 = DH*KP1
    unsigned short* wt2  = wt1f + NFRAG * 8;             // DH*DH

    const int TB = 256;
    k_init<<<(NN + TB - 1) / TB, TB, 0, stream>>>(cnt, fill, pooled, gcnt);
    k_hist<<<(NE + TB - 1) / TB, TB, 0, stream>>>(dst, cnt);
    k_scan1<<<NSB, SCB, 0, stream>>>(cnt, rowptr, bsum, dis);
    k_scan2<<<1, 256, 0, stream>>>(bsum, rowptr);
    k_scan3<<<NSB, SCB, 0, stream>>>(rowptr, bsum);
    k_scatter<<<(NE + TB - 1) / TB, TB, 0, stream>>>(src, dst, rowptr, fill, esrc);
    k_wt1f<<<(NFRAG * 8 + TB - 1) / TB, TB, 0, stream>>>(W1, wt1f);
    k_wt<<<(DH * DH + TB - 1) / TB, TB, 0, stream>>>(W2, wt2, DH, DH);

    // layer 1
    k_gemm1<<<(NN + 63) / 64, 256, 0, stream>>>(x, wt1f, ht);
    k_agg<true><<<(NN * QH + TB - 1) / TB, TB, 0, stream>>>(
        (const float4*)ht, dis, rowptr, esrc, (const float4*)b1,
        nullptr, (ushort4*)h1b);
    // layer 2
    k_gemm2<<<(NN + 63) / 64, 256, 0, stream>>>(h1b, wt2, ht);
    k_agg<false><<<(NN * QH + TB - 1) / TB, TB, 0, stream>>>(
        (const float4*)ht, dis, rowptr, esrc, (const float4*)b2,
        (float4*)hbuf, nullptr);
    // pool + fc
    k_pool_partial<<<(NN + PNODES - 1) / PNODES, 128, 0, stream>>>(hbuf, batch, pooled, gcnt);
    k_fc<<<1, 128, 0, stream>>>(pooled, gcnt, Wfc, bfc, out);
}

// Round 12
// 325.500 us; speedup vs baseline: 2.6066x; 1.0637x over previous
//
#include <hip/hip_runtime.h>
#include <hip/hip_bf16.h>

#define NN 50000
#define NE 800000
#define DIN 300
#define KP1 320
#define DH 96
#define DOUTC 2
#define NG 64

#define SCB 256
#define NSB ((NN + SCB - 1) / SCB)   // 196 scan blocks

#define NKB 10                        // gemm1 k-blocks (320/32)
#define NFRAG (NKB * 6 * 64)          // 3840 B-fragments of 16 B

typedef __attribute__((ext_vector_type(8))) short bf16x8;
typedef __attribute__((ext_vector_type(4))) float f32x4;

__device__ inline unsigned short f2bf(float f) {
    unsigned int u = __float_as_uint(f);
    unsigned int r = (u + 0x7fffu + ((u >> 16) & 1u)) >> 16;
    return (unsigned short)r;
}

// ---------------- CSR build ----------------
__global__ void k_init(int* cnt, int* fill, float* pooled, int* gcnt) {
    int i = blockIdx.x * blockDim.x + threadIdx.x;
    if (i < NN) { cnt[i] = 0; fill[i] = 0; }
    if (i < NG * DH) pooled[i] = 0.f;
    if (i < NG) gcnt[i] = 0;
}

__global__ void k_hist(const int* __restrict__ dst, int* cnt) {
    int e = blockIdx.x * blockDim.x + threadIdx.x;
    if (e < NE) atomicAdd(&cnt[dst[e]], 1);
}

__global__ void k_scan1(const int* __restrict__ cnt, int* __restrict__ rowptr,
                        int* __restrict__ bsum, float* __restrict__ dis) {
    __shared__ int s[SCB];
    const int t = threadIdx.x;
    const int i = blockIdx.x * SCB + t;
    int v = (i < NN) ? cnt[i] : 0;
    if (i < NN) dis[i] = rsqrtf(1.0f + (float)v);
    s[t] = v;
    __syncthreads();
    #pragma unroll
    for (int off = 1; off < SCB; off <<= 1) {
        int u = (t >= off) ? s[t - off] : 0;
        __syncthreads();
        s[t] += u;
        __syncthreads();
    }
    if (i < NN) rowptr[i] = s[t] - v;
    if (t == SCB - 1) bsum[blockIdx.x] = s[t];
}

__global__ void k_scan2(int* __restrict__ bsum, int* __restrict__ rowptr) {
    __shared__ int s[256];
    const int t = threadIdx.x;
    int v = (t < NSB) ? bsum[t] : 0;
    s[t] = v;
    __syncthreads();
    #pragma unroll
    for (int off = 1; off < 256; off <<= 1) {
        int u = (t >= off) ? s[t - off] : 0;
        __syncthreads();
        s[t] += u;
        __syncthreads();
    }
    if (t < NSB) bsum[t] = s[t] - v;
    if (t == 255) rowptr[NN] = s[t];
}

__global__ void k_scan3(int* __restrict__ rowptr, const int* __restrict__ bsum) {
    int i = blockIdx.x * SCB + threadIdx.x;
    if (i < NN) rowptr[i] += bsum[blockIdx.x];
}

// ushort esrc: NN=50000 < 2^16. Region 3.2->1.6 MB halves the random-store
// line-churn (R11 NT-store lesson: L2 is the write-combiner for these).
__global__ void k_scatter(const int* __restrict__ src, const int* __restrict__ dst,
                          const int* __restrict__ rowptr, int* fill,
                          unsigned short* __restrict__ esrc) {
    int e = blockIdx.x * blockDim.x + threadIdx.x;
    if (e < NE) {
        int d = dst[e];
        int pos = rowptr[d] + atomicAdd(&fill[d], 1);
        esrc[pos] = (unsigned short)src[e];
    }
}

// ---------------- W2 -> W^T bf16 (row-major, gemm2) ----------------
__global__ void k_wt(const float* __restrict__ W, unsigned short* __restrict__ WT,
                     int K, int KPAD) {
    int i = blockIdx.x * blockDim.x + threadIdx.x;
    if (i >= DH * KPAD) return;
    int j = i / KPAD, k = i - j * KPAD;
    WT[i] = (k < K) ? f2bf(W[(size_t)k * DH + j]) : (unsigned short)0;
}

// ---------------- W1 -> fragment-major bf16 for gemm1 LDS staging ----------------
__global__ void k_wt1f(const float* __restrict__ W, unsigned short* __restrict__ WF) {
    int g = blockIdx.x * blockDim.x + threadIdx.x;   // over NFRAG*8
    if (g >= NFRAG * 8) return;
    int j = g & 7;
    int f = g >> 3;
    int lane = f & 63;
    int ft = f >> 6;        // i*6 + t
    int t = ft % 6;
    int i = ft / 6;
    int row = (lane & 15) + 16 * t;
    int col = i * 32 + (lane >> 4) * 8 + j;
    WF[g] = (col < DIN) ? f2bf(W[(size_t)col * DH + row]) : (unsigned short)0;
}

// ---------------- GEMM1: C[NN][96](f32) = x[NN][300] @ W1 ----------------
__global__ __launch_bounds__(256) void k_gemm1(const float* __restrict__ A,
        const unsigned short* __restrict__ WF, float* __restrict__ C) {
    __shared__ unsigned short ldsB[NFRAG * 8];   // 61440 B
    const int tid = threadIdx.x;
    {
        const uint4* srcv = (const uint4*)WF;
        uint4* dstv = (uint4*)ldsB;
        #pragma unroll
        for (int f = 0; f < NFRAG / 256; ++f)
            dstv[f * 256 + tid] = srcv[f * 256 + tid];
    }
    __syncthreads();

    const int wv = tid >> 6;
    const int lane = tid & 63;
    const int m = lane & 15;
    const int quad = lane >> 4;
    const int row = blockIdx.x * 64 + wv * 16 + m;
    const int arow = row < NN ? row : NN - 1;
    const float* ap = A + (size_t)arow * DIN + quad * 8;
    const float4 z4 = make_float4(0.f, 0.f, 0.f, 0.f);
    const bf16x8* lb = (const bf16x8*)ldsB;
    f32x4 acc[6];
    #pragma unroll
    for (int t = 0; t < 6; ++t) acc[t] = (f32x4){0.f, 0.f, 0.f, 0.f};

    float4 pa[4][2];
    #pragma unroll
    for (int i = 0; i < 3; ++i) {
        int kb = i * 32 + quad * 8;
        pa[i][0] = (kb + 4 <= DIN) ? *(const float4*)(ap + i * 32) : z4;
        pa[i][1] = (kb + 8 <= DIN) ? *(const float4*)(ap + i * 32 + 4) : z4;
    }

    #pragma unroll
    for (int i = 0; i < NKB; ++i) {
        if (i + 3 < NKB) {
            int kb = (i + 3) * 32 + quad * 8;
            pa[(i + 3) & 3][0] = (kb + 4 <= DIN) ? *(const float4*)(ap + (i + 3) * 32) : z4;
            pa[(i + 3) & 3][1] = (kb + 8 <= DIN) ? *(const float4*)(ap + (i + 3) * 32 + 4) : z4;
        }
        float4 a0 = pa[i & 3][0], a1 = pa[i & 3][1];
        bf16x8 af;
        af[0] = (short)f2bf(a0.x); af[1] = (short)f2bf(a0.y);
        af[2] = (short)f2bf(a0.z); af[3] = (short)f2bf(a0.w);
        af[4] = (short)f2bf(a1.x); af[5] = (short)f2bf(a1.y);
        af[6] = (short)f2bf(a1.z); af[7] = (short)f2bf(a1.w);
        #pragma unroll
        for (int t = 0; t < 6; ++t) {
            bf16x8 bf = lb[(i * 6 + t) * 64 + lane];
            acc[t] = __builtin_amdgcn_mfma_f32_16x16x32_bf16(af, bf, acc[t], 0, 0, 0);
        }
    }
    const int rbase = blockIdx.x * 64 + wv * 16 + quad * 4;
    #pragma unroll
    for (int r = 0; r < 4; ++r) {
        int rr = rbase + r;
        if (rr < NN) {
            float* cp = C + (size_t)rr * DH + m;
            #pragma unroll
            for (int t = 0; t < 6; ++t) cp[t * 16] = acc[t][r];
        }
    }
}

// ---------------- GEMM2: C[NN][96](f32) = a1b[NN][96](bf16) @ W2 ----------------
__global__ __launch_bounds__(256) void k_gemm2(const unsigned short* __restrict__ Ab,
        const unsigned short* __restrict__ WT, float* __restrict__ C) {
    const int tid = threadIdx.x;
    const int wv = tid >> 6;
    const int lane = tid & 63;
    const int m = lane & 15;
    const int quad = lane >> 4;
    const int row = blockIdx.x * 64 + wv * 16 + m;
    const int arow = row < NN ? row : NN - 1;
    const unsigned short* ap = Ab + (size_t)arow * DH + quad * 8;
    const unsigned short* wp = WT + (size_t)m * DH + quad * 8;
    bf16x8 af[3], bf[3][6];
    #pragma unroll
    for (int i = 0; i < 3; ++i) af[i] = *(const bf16x8*)(ap + i * 32);
    #pragma unroll
    for (int i = 0; i < 3; ++i)
        #pragma unroll
        for (int t = 0; t < 6; ++t)
            bf[i][t] = *(const bf16x8*)(wp + (size_t)t * 16 * DH + i * 32);
    f32x4 acc[6];
    #pragma unroll
    for (int t = 0; t < 6; ++t) acc[t] = (f32x4){0.f, 0.f, 0.f, 0.f};
    #pragma unroll
    for (int i = 0; i < 3; ++i)
        #pragma unroll
        for (int t = 0; t < 6; ++t)
            acc[t] = __builtin_amdgcn_mfma_f32_16x16x32_bf16(af[i], bf[i][t], acc[t], 0, 0, 0);
    const int rbase = blockIdx.x * 64 + wv * 16 + quad * 4;
    #pragma unroll
    for (int r = 0; r < 4; ++r) {
        int rr = rbase + r;
        if (rr < NN) {
            float* cp = C + (size_t)rr * DH + m;
            #pragma unroll
            for (int t = 0; t < 6; ++t) cp[t * 16] = acc[t][r];
        }
    }
}

// ---------------- aggregate + bias + relu (fp32 gather, 4-way MLP unroll) ----------------
#define QH (DH / 4)   // 24 float4 per node
template <bool BFOUT>
__global__ void k_agg(const float4* __restrict__ ht4, const float* __restrict__ dis,
                      const int* __restrict__ rowptr,
                      const unsigned short* __restrict__ esrc,
                      const float4* __restrict__ bias4, float4* __restrict__ fout,
                      ushort4* __restrict__ bout) {
    int gid = blockIdx.x * blockDim.x + threadIdx.x;
    if (gid >= NN * QH) return;
    int n = gid / QH;
    int q = gid - n * QH;
    int beg = rowptr[n], end = rowptr[n + 1];
    float dn = dis[n];
    float4 h0 = ht4[(size_t)n * QH + q];
    float4 acc = make_float4(dn * h0.x, dn * h0.y, dn * h0.z, dn * h0.w);
    int e = beg;
    for (; e + 3 < end; e += 4) {
        int s0 = esrc[e], s1 = esrc[e + 1], s2 = esrc[e + 2], s3 = esrc[e + 3];
        float d0 = dis[s0], d1 = dis[s1], d2 = dis[s2], d3 = dis[s3];
        float4 v0 = ht4[(size_t)s0 * QH + q];
        float4 v1 = ht4[(size_t)s1 * QH + q];
        float4 v2 = ht4[(size_t)s2 * QH + q];
        float4 v3 = ht4[(size_t)s3 * QH + q];
        acc.x = fmaf(d0, v0.x, acc.x); acc.y = fmaf(d0, v0.y, acc.y);
        acc.z = fmaf(d0, v0.z, acc.z); acc.w = fmaf(d0, v0.w, acc.w);
        acc.x = fmaf(d1, v1.x, acc.x); acc.y = fmaf(d1, v1.y, acc.y);
        acc.z = fmaf(d1, v1.z, acc.z); acc.w = fmaf(d1, v1.w, acc.w);
        acc.x = fmaf(d2, v2.x, acc.x); acc.y = fmaf(d2, v2.y, acc.y);
        acc.z = fmaf(d2, v2.z, acc.z); acc.w = fmaf(d2, v2.w, acc.w);
        acc.x = fmaf(d3, v3.x, acc.x); acc.y = fmaf(d3, v3.y, acc.y);
        acc.z = fmaf(d3, v3.z, acc.z); acc.w = fmaf(d3, v3.w, acc.w);
    }
    for (; e < end; ++e) {
        int s = esrc[e];
        float ds = dis[s];
        float4 v = ht4[(size_t)s * QH + q];
        acc.x = fmaf(ds, v.x, acc.x);
        acc.y = fmaf(ds, v.y, acc.y);
        acc.z = fmaf(ds, v.z, acc.z);
        acc.w = fmaf(ds, v.w, acc.w);
    }
    float4 b = bias4[q];
    float4 r;
    r.x = fmaxf(fmaf(dn, acc.x, b.x), 0.f);
    r.y = fmaxf(fmaf(dn, acc.y, b.y), 0.f);
    r.z = fmaxf(fmaf(dn, acc.z, b.z), 0.f);
    r.w = fmaxf(fmaf(dn, acc.w, b.w), 0.f);
    if (BFOUT) {
        ushort4 o;
        o.x = f2bf(r.x); o.y = f2bf(r.y); o.z = f2bf(r.z); o.w = f2bf(r.w);
        bout[gid] = o;
    } else {
        fout[gid] = r;
    }
}

// ---------------- mean-pool: node-parallel partial sums ----------------
#define PNODES 32
__global__ void k_pool_partial(const float* __restrict__ h, const int* __restrict__ batch,
                               float* __restrict__ pooled, int* __restrict__ gcnt) {
    __shared__ int sbatch[PNODES];
    const int n0 = blockIdx.x * PNODES;
    const int nend = min(n0 + PNODES, NN);
    const int cnt = nend - n0;
    const int f = threadIdx.x;   // 128 threads
    if (f < cnt) sbatch[f] = batch[n0 + f];
    __syncthreads();
    if (f < DH) {
        float acc = 0.f;
        int cur = sbatch[0];
        for (int i = 0; i < cnt; ++i) {
            int g = sbatch[i];
            if (g != cur) {
                atomicAdd(&pooled[cur * DH + f], acc);
                acc = 0.f; cur = g;
            }
            acc += h[(size_t)(n0 + i) * DH + f];
        }
        atomicAdd(&pooled[cur * DH + f], acc);
    } else if (f == DH) {
        int c = 0;
        int cur = sbatch[0];
        for (int i = 0; i < cnt; ++i) {
            int g = sbatch[i];
            if (g != cur) { atomicAdd(&gcnt[cur], c); c = 0; cur = g; }
            ++c;
        }
        atomicAdd(&gcnt[cur], c);
    }
}

__global__ void k_fc(const float* __restrict__ pooled, const int* __restrict__ gcnt,
                     const float* __restrict__ Wfc, const float* __restrict__ bfc,
                     float* __restrict__ out) {
    const int t = threadIdx.x;
    if (t >= NG * DOUTC) return;
    const int g = t / DOUTC;
    const int c = t - g * DOUTC;
    float inv = 1.f / fmaxf((float)gcnt[g], 1.f);
    float acc = bfc[c];
    #pragma unroll 8
    for (int j = 0; j < DH; ++j)
        acc += pooled[g * DH + j] * inv * Wfc[j * DOUTC + c];
    out[g * DOUTC + c] = acc;
}

extern "C" void kernel_launch(void* const* d_in, const int* in_sizes, int n_in,
                              void* d_out, int out_size, void* d_ws, size_t ws_size,
                              hipStream_t stream) {
    const float* x   = (const float*)d_in[0];
    const float* W1  = (const float*)d_in[1];
    const float* b1  = (const float*)d_in[2];
    const float* W2  = (const float*)d_in[3];
    const float* b2  = (const float*)d_in[4];
    const float* Wfc = (const float*)d_in[5];
    const float* bfc = (const float*)d_in[6];
    const int* src   = (const int*)d_in[7];
    const int* dst   = (const int*)d_in[8];
    const int* batch = (const int*)d_in[9];
    float* out = (float*)d_out;

    float* ht    = (float*)d_ws;              // NN*DH f32 (both GEMM outputs)
    float* hbuf  = ht + (size_t)NN * DH;      // NN*DH f32 (agg2 out)
    unsigned short* h1b = (unsigned short*)hbuf; // NN*DH bf16 (agg1 out, overlay)
    float* dis   = hbuf + (size_t)NN * DH;    // NN
    float* pooled= dis + NN;                  // NG*DH
    int* cnt     = (int*)(pooled + NG * DH);  // NN
    int* fill    = cnt + NN;                  // NN
    int* gcnt    = fill + NN;                 // NG
    int* rowptr  = gcnt + NG;                 // NN+1
    int* bsum    = rowptr + NN + 2;           // NSB
    unsigned short* esrc = (unsigned short*)(bsum + NSB);  // NE ushort
    unsigned short* wt1f = esrc + NE;                      // NFRAG*8 = DH*KP1
    unsigned short* wt2  = wt1f + NFRAG * 8;               // DH*DH

    const int TB = 256;
    k_init<<<(NN + TB - 1) / TB, TB, 0, stream>>>(cnt, fill, pooled, gcnt);
    k_hist<<<(NE + TB - 1) / TB, TB, 0, stream>>>(dst, cnt);
    k_scan1<<<NSB, SCB, 0, stream>>>(cnt, rowptr, bsum, dis);
    k_scan2<<<1, 256, 0, stream>>>(bsum, rowptr);
    k_scan3<<<NSB, SCB, 0, stream>>>(rowptr, bsum);
    k_scatter<<<(NE + TB - 1) / TB, TB, 0, stream>>>(src, dst, rowptr, fill, esrc);
    k_wt1f<<<(NFRAG * 8 + TB - 1) / TB, TB, 0, stream>>>(W1, wt1f);
    k_wt<<<(DH * DH + TB - 1) / TB, TB, 0, stream>>>(W2, wt2, DH, DH);

    // layer 1
    k_gemm1<<<(NN + 63) / 64, 256, 0, stream>>>(x, wt1f, ht);
    k_agg<true><<<(NN * QH + TB - 1) / TB, TB, 0, stream>>>(
        (const float4*)ht, dis, rowptr, esrc, (const float4*)b1,
        nullptr, (ushort4*)h1b);
    // layer 2
    k_gemm2<<<(NN + 63) / 64, 256, 0, stream>>>(h1b, wt2, ht);
    k_agg<false><<<(NN * QH + TB - 1) / TB, TB, 0, stream>>>(
        (const float4*)ht, dis, rowptr, esrc, (const float4*)b2,
        (float4*)hbuf, nullptr);
    // pool + fc
    k_pool_partial<<<(NN + PNODES - 1) / PNODES, 128, 0, stream>>>(hbuf, batch, pooled, gcnt);
    k_fc<<<1, 128, 0, stream>>>(pooled, gcnt, Wfc, bfc, out);
}

// Round 13
// 298.566 us; speedup vs baseline: 2.8417x; 1.0902x over previous
//
#include <hip/hip_runtime.h>
#include <hip/hip_bf16.h>

#define NN 50000
#define NE 800000
#define DIN 300
#define KP1 320
#define DH 96
#define DOUTC 2
#define NG 64

#define SCB 256
#define NSB ((NN + SCB - 1) / SCB)   // 196 scan blocks

#define NKB 10                        // gemm1 k-blocks (320/32)
#define NFRAG (NKB * 6 * 64)          // 3840 B-fragments of 16 B

typedef __attribute__((ext_vector_type(8))) short bf16x8;
typedef __attribute__((ext_vector_type(4))) float f32x4;

__device__ inline unsigned short f2bf(float f) {
    unsigned int u = __float_as_uint(f);
    unsigned int r = (u + 0x7fffu + ((u >> 16) & 1u)) >> 16;
    return (unsigned short)r;
}
__device__ inline float b2f(unsigned short u) {
    return __uint_as_float((unsigned int)u << 16);
}

// ---------------- CSR build ----------------
__global__ void k_init(int* cnt, int* fill, float* pooled, int* gcnt) {
    int i = blockIdx.x * blockDim.x + threadIdx.x;
    if (i < NN) { cnt[i] = 0; fill[i] = 0; }
    if (i < NG * DH) pooled[i] = 0.f;
    if (i < NG) gcnt[i] = 0;
}

__global__ void k_hist(const int* __restrict__ dst, int* cnt) {
    int e = blockIdx.x * blockDim.x + threadIdx.x;
    if (e < NE) atomicAdd(&cnt[dst[e]], 1);
}

__global__ void k_scan1(const int* __restrict__ cnt, int* __restrict__ rowptr,
                        int* __restrict__ bsum, float* __restrict__ dis) {
    __shared__ int s[SCB];
    const int t = threadIdx.x;
    const int i = blockIdx.x * SCB + t;
    int v = (i < NN) ? cnt[i] : 0;
    if (i < NN) dis[i] = rsqrtf(1.0f + (float)v);
    s[t] = v;
    __syncthreads();
    #pragma unroll
    for (int off = 1; off < SCB; off <<= 1) {
        int u = (t >= off) ? s[t - off] : 0;
        __syncthreads();
        s[t] += u;
        __syncthreads();
    }
    if (i < NN) rowptr[i] = s[t] - v;
    if (t == SCB - 1) bsum[blockIdx.x] = s[t];
}

__global__ void k_scan2(int* __restrict__ bsum, int* __restrict__ rowptr) {
    __shared__ int s[256];
    const int t = threadIdx.x;
    int v = (t < NSB) ? bsum[t] : 0;
    s[t] = v;
    __syncthreads();
    #pragma unroll
    for (int off = 1; off < 256; off <<= 1) {
        int u = (t >= off) ? s[t - off] : 0;
        __syncthreads();
        s[t] += u;
        __syncthreads();
    }
    if (t < NSB) bsum[t] = s[t] - v;
    if (t == 255) rowptr[NN] = s[t];
}

__global__ void k_scan3(int* __restrict__ rowptr, const int* __restrict__ bsum) {
    int i = blockIdx.x * SCB + threadIdx.x;
    if (i < NN) rowptr[i] += bsum[blockIdx.x];
}

__global__ void k_scatter(const int* __restrict__ src, const int* __restrict__ dst,
                          const int* __restrict__ rowptr, int* fill,
                          unsigned short* __restrict__ esrc) {
    int e = blockIdx.x * blockDim.x + threadIdx.x;
    if (e < NE) {
        int d = dst[e];
        int pos = rowptr[d] + atomicAdd(&fill[d], 1);
        esrc[pos] = (unsigned short)src[e];
    }
}

// ---------------- W2 -> W^T bf16 (row-major, gemm2) ----------------
__global__ void k_wt(const float* __restrict__ W, unsigned short* __restrict__ WT,
                     int K, int KPAD) {
    int i = blockIdx.x * blockDim.x + threadIdx.x;
    if (i >= DH * KPAD) return;
    int j = i / KPAD, k = i - j * KPAD;
    WT[i] = (k < K) ? f2bf(W[(size_t)k * DH + j]) : (unsigned short)0;
}

// ---------------- W1 -> fragment-major bf16 for gemm1 LDS staging ----------------
__global__ void k_wt1f(const float* __restrict__ W, unsigned short* __restrict__ WF) {
    int g = blockIdx.x * blockDim.x + threadIdx.x;   // over NFRAG*8
    if (g >= NFRAG * 8) return;
    int j = g & 7;
    int f = g >> 3;
    int lane = f & 63;
    int ft = f >> 6;        // i*6 + t
    int t = ft % 6;
    int i = ft / 6;
    int row = (lane & 15) + 16 * t;
    int col = i * 32 + (lane >> 4) * 8 + j;
    WF[g] = (col < DIN) ? f2bf(W[(size_t)col * DH + row]) : (unsigned short)0;
}

// ---------------- GEMM1: hb[NN][96](bf16) = x[NN][300] @ W1 ----------------
__global__ __launch_bounds__(256) void k_gemm1(const float* __restrict__ A,
        const unsigned short* __restrict__ WF, unsigned short* __restrict__ Cb) {
    __shared__ unsigned short ldsB[NFRAG * 8];   // 61440 B
    const int tid = threadIdx.x;
    {
        const uint4* srcv = (const uint4*)WF;
        uint4* dstv = (uint4*)ldsB;
        #pragma unroll
        for (int f = 0; f < NFRAG / 256; ++f)
            dstv[f * 256 + tid] = srcv[f * 256 + tid];
    }
    __syncthreads();

    const int wv = tid >> 6;
    const int lane = tid & 63;
    const int m = lane & 15;
    const int quad = lane >> 4;
    const int row = blockIdx.x * 64 + wv * 16 + m;
    const int arow = row < NN ? row : NN - 1;
    const float* ap = A + (size_t)arow * DIN + quad * 8;
    const float4 z4 = make_float4(0.f, 0.f, 0.f, 0.f);
    const bf16x8* lb = (const bf16x8*)ldsB;
    f32x4 acc[6];
    #pragma unroll
    for (int t = 0; t < 6; ++t) acc[t] = (f32x4){0.f, 0.f, 0.f, 0.f};

    float4 pa[4][2];
    #pragma unroll
    for (int i = 0; i < 3; ++i) {
        int kb = i * 32 + quad * 8;
        pa[i][0] = (kb + 4 <= DIN) ? *(const float4*)(ap + i * 32) : z4;
        pa[i][1] = (kb + 8 <= DIN) ? *(const float4*)(ap + i * 32 + 4) : z4;
    }

    #pragma unroll
    for (int i = 0; i < NKB; ++i) {
        if (i + 3 < NKB) {
            int kb = (i + 3) * 32 + quad * 8;
            pa[(i + 3) & 3][0] = (kb + 4 <= DIN) ? *(const float4*)(ap + (i + 3) * 32) : z4;
            pa[(i + 3) & 3][1] = (kb + 8 <= DIN) ? *(const float4*)(ap + (i + 3) * 32 + 4) : z4;
        }
        float4 a0 = pa[i & 3][0], a1 = pa[i & 3][1];
        bf16x8 af;
        af[0] = (short)f2bf(a0.x); af[1] = (short)f2bf(a0.y);
        af[2] = (short)f2bf(a0.z); af[3] = (short)f2bf(a0.w);
        af[4] = (short)f2bf(a1.x); af[5] = (short)f2bf(a1.y);
        af[6] = (short)f2bf(a1.z); af[7] = (short)f2bf(a1.w);
        #pragma unroll
        for (int t = 0; t < 6; ++t) {
            bf16x8 bf = lb[(i * 6 + t) * 64 + lane];
            acc[t] = __builtin_amdgcn_mfma_f32_16x16x32_bf16(af, bf, acc[t], 0, 0, 0);
        }
    }
    const int rbase = blockIdx.x * 64 + wv * 16 + quad * 4;
    #pragma unroll
    for (int r = 0; r < 4; ++r) {
        int rr = rbase + r;
        if (rr < NN) {
            unsigned short* cp = Cb + (size_t)rr * DH + m;
            #pragma unroll
            for (int t = 0; t < 6; ++t) cp[t * 16] = f2bf(acc[t][r]);
        }
    }
}

// ---------------- GEMM2: hb[NN][96](bf16) = a1b[NN][96](bf16) @ W2 ----------------
__global__ __launch_bounds__(256) void k_gemm2(const unsigned short* __restrict__ Ab,
        const unsigned short* __restrict__ WT, unsigned short* __restrict__ Cb) {
    const int tid = threadIdx.x;
    const int wv = tid >> 6;
    const int lane = tid & 63;
    const int m = lane & 15;
    const int quad = lane >> 4;
    const int row = blockIdx.x * 64 + wv * 16 + m;
    const int arow = row < NN ? row : NN - 1;
    const unsigned short* ap = Ab + (size_t)arow * DH + quad * 8;
    const unsigned short* wp = WT + (size_t)m * DH + quad * 8;
    bf16x8 af[3], bf[3][6];
    #pragma unroll
    for (int i = 0; i < 3; ++i) af[i] = *(const bf16x8*)(ap + i * 32);
    #pragma unroll
    for (int i = 0; i < 3; ++i)
        #pragma unroll
        for (int t = 0; t < 6; ++t)
            bf[i][t] = *(const bf16x8*)(wp + (size_t)t * 16 * DH + i * 32);
    f32x4 acc[6];
    #pragma unroll
    for (int t = 0; t < 6; ++t) acc[t] = (f32x4){0.f, 0.f, 0.f, 0.f};
    #pragma unroll
    for (int i = 0; i < 3; ++i)
        #pragma unroll
        for (int t = 0; t < 6; ++t)
            acc[t] = __builtin_amdgcn_mfma_f32_16x16x32_bf16(af[i], bf[i][t], acc[t], 0, 0, 0);
    const int rbase = blockIdx.x * 64 + wv * 16 + quad * 4;
    #pragma unroll
    for (int r = 0; r < 4; ++r) {
        int rr = rbase + r;
        if (rr < NN) {
            unsigned short* cp = Cb + (size_t)rr * DH + m;
            #pragma unroll
            for (int t = 0; t < 6; ++t) cp[t * 16] = f2bf(acc[t][r]);
        }
    }
}

// ---------------- aggregate + bias + relu (bf16 gather, 4-way MLP unroll) ----------------
#define QH (DH / 4)   // 24 ushort4 lanes per node
template <bool BFOUT>
__global__ void k_agg(const ushort4* __restrict__ hb, const float* __restrict__ dis,
                      const int* __restrict__ rowptr,
                      const unsigned short* __restrict__ esrc,
                      const float4* __restrict__ bias4, float4* __restrict__ fout,
                      ushort4* __restrict__ bout) {
    int gid = blockIdx.x * blockDim.x + threadIdx.x;
    if (gid >= NN * QH) return;
    int n = gid / QH;
    int q = gid - n * QH;
    int beg = rowptr[n], end = rowptr[n + 1];
    float dn = dis[n];
    ushort4 u0 = hb[(size_t)n * QH + q];
    float4 acc = make_float4(dn * b2f(u0.x), dn * b2f(u0.y), dn * b2f(u0.z), dn * b2f(u0.w));
    int e = beg;
    for (; e + 3 < end; e += 4) {
        int s0 = esrc[e], s1 = esrc[e + 1], s2 = esrc[e + 2], s3 = esrc[e + 3];
        float d0 = dis[s0], d1 = dis[s1], d2 = dis[s2], d3 = dis[s3];
        ushort4 v0 = hb[(size_t)s0 * QH + q];
        ushort4 v1 = hb[(size_t)s1 * QH + q];
        ushort4 v2 = hb[(size_t)s2 * QH + q];
        ushort4 v3 = hb[(size_t)s3 * QH + q];
        acc.x = fmaf(d0, b2f(v0.x), acc.x); acc.y = fmaf(d0, b2f(v0.y), acc.y);
        acc.z = fmaf(d0, b2f(v0.z), acc.z); acc.w = fmaf(d0, b2f(v0.w), acc.w);
        acc.x = fmaf(d1, b2f(v1.x), acc.x); acc.y = fmaf(d1, b2f(v1.y), acc.y);
        acc.z = fmaf(d1, b2f(v1.z), acc.z); acc.w = fmaf(d1, b2f(v1.w), acc.w);
        acc.x = fmaf(d2, b2f(v2.x), acc.x); acc.y = fmaf(d2, b2f(v2.y), acc.y);
        acc.z = fmaf(d2, b2f(v2.z), acc.z); acc.w = fmaf(d2, b2f(v2.w), acc.w);
        acc.x = fmaf(d3, b2f(v3.x), acc.x); acc.y = fmaf(d3, b2f(v3.y), acc.y);
        acc.z = fmaf(d3, b2f(v3.z), acc.z); acc.w = fmaf(d3, b2f(v3.w), acc.w);
    }
    for (; e < end; ++e) {
        int s = esrc[e];
        float ds = dis[s];
        ushort4 v = hb[(size_t)s * QH + q];
        acc.x = fmaf(ds, b2f(v.x), acc.x);
        acc.y = fmaf(ds, b2f(v.y), acc.y);
        acc.z = fmaf(ds, b2f(v.z), acc.z);
        acc.w = fmaf(ds, b2f(v.w), acc.w);
    }
    float4 b = bias4[q];
    float4 r;
    r.x = fmaxf(fmaf(dn, acc.x, b.x), 0.f);
    r.y = fmaxf(fmaf(dn, acc.y, b.y), 0.f);
    r.z = fmaxf(fmaf(dn, acc.z, b.z), 0.f);
    r.w = fmaxf(fmaf(dn, acc.w, b.w), 0.f);
    if (BFOUT) {
        ushort4 o;
        o.x = f2bf(r.x); o.y = f2bf(r.y); o.z = f2bf(r.z); o.w = f2bf(r.w);
        bout[gid] = o;
    } else {
        fout[gid] = r;
    }
}

// ---------------- mean-pool: node-parallel partial sums ----------------
#define PNODES 32
__global__ void k_pool_partial(const float* __restrict__ h, const int* __restrict__ batch,
                               float* __restrict__ pooled, int* __restrict__ gcnt) {
    __shared__ int sbatch[PNODES];
    const int n0 = blockIdx.x * PNODES;
    const int nend = min(n0 + PNODES, NN);
    const int cnt = nend - n0;
    const int f = threadIdx.x;   // 128 threads
    if (f < cnt) sbatch[f] = batch[n0 + f];
    __syncthreads();
    if (f < DH) {
        float acc = 0.f;
        int cur = sbatch[0];
        for (int i = 0; i < cnt; ++i) {
            int g = sbatch[i];
            if (g != cur) {
                atomicAdd(&pooled[cur * DH + f], acc);
                acc = 0.f; cur = g;
            }
            acc += h[(size_t)(n0 + i) * DH + f];
        }
        atomicAdd(&pooled[cur * DH + f], acc);
    } else if (f == DH) {
        int c = 0;
        int cur = sbatch[0];
        for (int i = 0; i < cnt; ++i) {
            int g = sbatch[i];
            if (g != cur) { atomicAdd(&gcnt[cur], c); c = 0; cur = g; }
            ++c;
        }
        atomicAdd(&gcnt[cur], c);
    }
}

__global__ void k_fc(const float* __restrict__ pooled, const int* __restrict__ gcnt,
                     const float* __restrict__ Wfc, const float* __restrict__ bfc,
                     float* __restrict__ out) {
    const int t = threadIdx.x;
    if (t >= NG * DOUTC) return;
    const int g = t / DOUTC;
    const int c = t - g * DOUTC;
    float inv = 1.f / fmaxf((float)gcnt[g], 1.f);
    float acc = bfc[c];
    #pragma unroll 8
    for (int j = 0; j < DH; ++j)
        acc += pooled[g * DH + j] * inv * Wfc[j * DOUTC + c];
    out[g * DOUTC + c] = acc;
}

extern "C" void kernel_launch(void* const* d_in, const int* in_sizes, int n_in,
                              void* d_out, int out_size, void* d_ws, size_t ws_size,
                              hipStream_t stream) {
    const float* x   = (const float*)d_in[0];
    const float* W1  = (const float*)d_in[1];
    const float* b1  = (const float*)d_in[2];
    const float* W2  = (const float*)d_in[3];
    const float* b2  = (const float*)d_in[4];
    const float* Wfc = (const float*)d_in[5];
    const float* bfc = (const float*)d_in[6];
    const int* src   = (const int*)d_in[7];
    const int* dst   = (const int*)d_in[8];
    const int* batch = (const int*)d_in[9];
    float* out = (float*)d_out;

    // hb (bf16) is reused for both GEMM outputs: gemm1->hb, agg1 gathers hb
    // -> a1b, gemm2 reads a1b -> hb (hb dead after agg1), agg2 gathers hb
    // -> hbuf (fp32). Stream-ordered, safe.
    unsigned short* hb  = (unsigned short*)d_ws;        // NN*DH bf16
    unsigned short* a1b = hb + (size_t)NN * DH;         // NN*DH bf16
    float* hbuf  = (float*)(a1b + (size_t)NN * DH);     // NN*DH f32
    float* dis   = hbuf + (size_t)NN * DH;              // NN
    float* pooled= dis + NN;                            // NG*DH
    int* cnt     = (int*)(pooled + NG * DH);            // NN
    int* fill    = cnt + NN;                            // NN
    int* gcnt    = fill + NN;                           // NG
    int* rowptr  = gcnt + NG;                           // NN+1
    int* bsum    = rowptr + NN + 2;                     // NSB
    unsigned short* esrc = (unsigned short*)(bsum + NSB);  // NE ushort
    unsigned short* wt1f = esrc + NE;                      // NFRAG*8
    unsigned short* wt2  = wt1f + NFRAG * 8;               // DH*DH

    const int TB = 256;
    k_init<<<(NN + TB - 1) / TB, TB, 0, stream>>>(cnt, fill, pooled, gcnt);
    k_hist<<<(NE + TB - 1) / TB, TB, 0, stream>>>(dst, cnt);
    k_scan1<<<NSB, SCB, 0, stream>>>(cnt, rowptr, bsum, dis);
    k_scan2<<<1, 256, 0, stream>>>(bsum, rowptr);
    k_scan3<<<NSB, SCB, 0, stream>>>(rowptr, bsum);
    k_scatter<<<(NE + TB - 1) / TB, TB, 0, stream>>>(src, dst, rowptr, fill, esrc);
    k_wt1f<<<(NFRAG * 8 + TB - 1) / TB, TB, 0, stream>>>(W1, wt1f);
    k_wt<<<(DH * DH + TB - 1) / TB, TB, 0, stream>>>(W2, wt2, DH, DH);

    // layer 1
    k_gemm1<<<(NN + 63) / 64, 256, 0, stream>>>(x, wt1f, hb);
    k_agg<true><<<(NN * QH + TB - 1) / TB, TB, 0, stream>>>(
        (const ushort4*)hb, dis, rowptr, esrc, (const float4*)b1,
        nullptr, (ushort4*)a1b);
    // layer 2
    k_gemm2<<<(NN + 63) / 64, 256, 0, stream>>>(a1b, wt2, hb);
    k_agg<false><<<(NN * QH + TB - 1) / TB, TB, 0, stream>>>(
        (const ushort4*)hb, dis, rowptr, esrc, (const float4*)b2,
        (float4*)hbuf, nullptr);
    // pool + fc
    k_pool_partial<<<(NN + PNODES - 1) / PNODES, 128, 0, stream>>>(hbuf, batch, pooled, gcnt);
    k_fc<<<1, 128, 0, stream>>>(pooled, gcnt, Wfc, bfc, out);
}